// Round 14
// baseline (365.577 us; speedup 1.0000x reference)
//
#include <hip/hip_runtime.h>

#define NEG_SLOPE 0.2f
#define EPSF 1e-16f
#define SEG_SHIFT 13   // src segment = src >> 13 (8192 rows = 2 MB of h2)

typedef unsigned int uint;
typedef unsigned short ushort;
typedef __attribute__((ext_vector_type(8))) short short8;   // 8 bf16 (4 VGPRs)
typedef __attribute__((ext_vector_type(4))) float floatx4;  // MFMA acc
typedef __attribute__((ext_vector_type(4))) uint uintx4;    // nontemporal 16B
typedef __attribute__((ext_vector_type(2))) uint uintx2;    // nontemporal 8B

// RNE float->bf16
static __device__ __forceinline__ ushort f2bf(float f) {
    uint u = __float_as_uint(f);
    return (ushort)((u + 0x7FFFu + ((u >> 16) & 1u)) >> 16);
}
static __device__ __forceinline__ uint pack2(float a, float b) {
    return (uint)f2bf(a) | ((uint)f2bf(b) << 16);
}
static __device__ __forceinline__ float bf_lo(uint p) { return __uint_as_float(p << 16); }
static __device__ __forceinline__ float bf_hi(uint p) { return __uint_as_float(p & 0xFFFF0000u); }
static __device__ __forceinline__ short8 u2s8(uint4 v) {
    union { uint4 u; short8 s; } c; c.u = v; return c.s;
}
// async global->LDS, 16B per lane, dst = wave-uniform base + lane*16
static __device__ __forceinline__ void load_lds16(const void* g, void* l) {
    __builtin_amdgcn_global_load_lds(
        (const __attribute__((address_space(1))) void*)g,
        (__attribute__((address_space(3))) void*)l, 16, 0, 0);
}

#define GA_LDS_BYTES (2048 * 16 + 16 * 65 * 16)   // sW + sX = 49408

// ============================================================ GEMM + alpha body (MFMA, transposed)
static __device__ __forceinline__ void gemm_body(
    char* smraw, const uint4* __restrict__ xb, const uint4* __restrict__ Wp,
    const float* __restrict__ att_s, const float* __restrict__ att_d,
    uint* __restrict__ h2, float* __restrict__ alpha_s,
    float* __restrict__ alpha_d, int N, int rowBase)
{
    uint4* sW = (uint4*)smraw;                 // 2048 slots (linear copy of Wp)
    uint4* sX = sW + 2048;                     // 16 chunks * 65 slots

    const int t = threadIdx.x;
    const int wb = t & ~63;

#pragma unroll
    for (int i = 0; i < 8; ++i)
        load_lds16(Wp + i * 256 + t, sW + i * 256 + wb);

#pragma unroll
    for (int i = 0; i < 4; ++i) {
        int f = t + i * 256;
        int row = f >> 4, c8 = f & 15;
        uint4 v = make_uint4(0u, 0u, 0u, 0u);
        if (rowBase + row < N) v = xb[(size_t)(rowBase + row) * 16 + c8];
        sX[c8 * 65 + row] = v;
    }
    __syncthreads();

    const int w = t >> 6, lane = t & 63, q = lane >> 4, l15 = lane & 15;
    short8 xf[4];
#pragma unroll
    for (int s = 0; s < 4; ++s)
        xf[s] = u2s8(sX[(4 * s + q) * 65 + 16 * w + l15]);

    floatx4 acc[8];
#pragma unroll
    for (int ct = 0; ct < 8; ++ct) acc[ct] = (floatx4){0.f, 0.f, 0.f, 0.f};
#pragma unroll
    for (int ct = 0; ct < 8; ++ct) {
#pragma unroll
        for (int s = 0; s < 4; ++s) {
            short8 wf = u2s8(sW[(4 * s + q) * 128 + 16 * ct + l15]);
            acc[ct] = __builtin_amdgcn_mfma_f32_16x16x32_bf16(wf, xf[s], acc[ct], 0, 0, 0);
        }
    }

    const int node = rowBase + 16 * w + l15;
    if (node < N) {
        uint2* hp = (uint2*)(h2 + (size_t)node * 64);
#pragma unroll
        for (int ct = 0; ct < 8; ++ct) {
            uint2 o;
            o.x = pack2(acc[ct][0], acc[ct][1]);
            o.y = pack2(acc[ct][2], acc[ct][3]);
            hp[4 * ct + q] = o;
        }
    }
    float ps[4], pd[4];
#pragma unroll
    for (int hd = 0; hd < 4; ++hd) {
        const float4 as0 = *(const float4*)(att_s + 32 * hd + 4 * q);
        const float4 as1 = *(const float4*)(att_s + 32 * hd + 16 + 4 * q);
        const float4 ad0 = *(const float4*)(att_d + 32 * hd + 4 * q);
        const float4 ad1 = *(const float4*)(att_d + 32 * hd + 16 + 4 * q);
        floatx4 c0 = acc[2 * hd], c1 = acc[2 * hd + 1];
        ps[hd] = c0[0] * as0.x + c0[1] * as0.y + c0[2] * as0.z + c0[3] * as0.w
               + c1[0] * as1.x + c1[1] * as1.y + c1[2] * as1.z + c1[3] * as1.w;
        pd[hd] = c0[0] * ad0.x + c0[1] * ad0.y + c0[2] * ad0.z + c0[3] * ad0.w
               + c1[0] * ad1.x + c1[1] * ad1.y + c1[2] * ad1.z + c1[3] * ad1.w;
    }
#pragma unroll
    for (int hd = 0; hd < 4; ++hd) {
        ps[hd] += __shfl_xor(ps[hd], 16);
        ps[hd] += __shfl_xor(ps[hd], 32);
        pd[hd] += __shfl_xor(pd[hd], 16);
        pd[hd] += __shfl_xor(pd[hd], 32);
    }
    if (node < N) {
        alpha_s[(size_t)node * 4 + q] = ps[q];
        alpha_d[(size_t)node * 4 + q] = pd[q];
    }
}

// ============================================================ prep + bucket count (fused)
__global__ __launch_bounds__(256) void prep_count_kernel(
    const float* __restrict__ W, const float* __restrict__ W1,
    const float* __restrict__ x, uint4* __restrict__ Wp,
    uint4* __restrict__ W1p, uint4* __restrict__ xb,
    const int* __restrict__ ei, int E, int NB,
    int* __restrict__ bucket_count, int L, int N, int nbPrep)
{
    __shared__ int cnt[256];
    if ((int)blockIdx.x >= nbPrep) {
        cnt[threadIdx.x] = 0;
        __syncthreads();
        const int base = (blockIdx.x - nbPrep) * 2048 + threadIdx.x;
#pragma unroll
        for (int j = 0; j < 8; ++j) {
            int idx = base + j * 256;
            if (idx < E) atomicAdd(&cnt[ei[E + idx] >> 8], 1);
        }
        __syncthreads();
        int c = cnt[threadIdx.x];
        if ((int)threadIdx.x < NB && c) atomicAdd(&bucket_count[threadIdx.x], c);
        return;
    }
    int id = blockIdx.x * 256 + threadIdx.x;
    const int nW = L * 2048;
    const int nX = N * 16;
    if (id < nW) {
        int l = id >> 11, s = id & 2047;
        int chunk = s >> 7, col = s & 127;
        const float* wp = W + (size_t)l * 16384 + (chunk * 8) * 128 + col;
        uint4 pk;
        pk.x = pack2(wp[0],   wp[128]);
        pk.y = pack2(wp[256], wp[384]);
        pk.z = pack2(wp[512], wp[640]);
        pk.w = pack2(wp[768], wp[896]);
        Wp[id] = pk;
    } else if (id < nW + 1024) {
        int s = id - nW;
        int chunk = s >> 5, col = s & 31;
        const float* wp = W1 + (chunk * 8) * 32 + col;
        uint4 pk;
        pk.x = pack2(wp[0],   wp[32]);
        pk.y = pack2(wp[64],  wp[96]);
        pk.z = pack2(wp[128], wp[160]);
        pk.w = pack2(wp[192], wp[224]);
        W1p[s] = pk;
    } else if (id < nW + 1024 + nX) {
        int xid = id - nW - 1024;
        int row = xid >> 4, c8 = xid & 15;
        const float4* xp = (const float4*)(x + (size_t)row * 128 + c8 * 8);
        float4 v0 = xp[0], v1 = xp[1];
        uint4 pk;
        pk.x = pack2(v0.x, v0.y); pk.y = pack2(v0.z, v0.w);
        pk.z = pack2(v1.x, v1.y); pk.w = pack2(v1.z, v1.w);
        xb[xid] = pk;
    }
}

// ============================================================ distribute + gemm l0 (grid-fused)
__global__ __launch_bounds__(256) void dist_gemm_kernel(
    const int* __restrict__ ei, int E, int NB,
    const int* __restrict__ bucket_count, int* __restrict__ bucket_cursor,
    uint* __restrict__ bdata, int nbEd,
    const uint4* __restrict__ xb, const uint4* __restrict__ Wp,
    const float* __restrict__ att_s, const float* __restrict__ att_d,
    uint* __restrict__ h2, float* __restrict__ alpha_s,
    float* __restrict__ alpha_d, int N)
{
    __shared__ __align__(16) char smraw[GA_LDS_BYTES];
    const int t = threadIdx.x;
    if ((int)blockIdx.x >= nbEd) {
        gemm_body(smraw, xb, Wp, att_s, att_d, h2, alpha_s, alpha_d, N,
                  (blockIdx.x - nbEd) * 64);
        return;
    }
    int* cnt = (int*)smraw;        // 256
    int* sc  = cnt + 256;          // 256
    int* bb  = sc + 256;           // 256
    cnt[t] = 0;
    __syncthreads();
    const int base = blockIdx.x * 2048 + t;
    int srcs[8], dsts[8], rank[8];
#pragma unroll
    for (int j = 0; j < 8; ++j) {
        int idx = base + j * 256;
        if (idx < E) {
            srcs[j] = ei[idx];
            dsts[j] = ei[E + idx];
            rank[j] = atomicAdd(&cnt[dsts[j] >> 8], 1);
        } else dsts[j] = -1;
    }
    __syncthreads();
    int bc = (t < NB) ? bucket_count[t] : 0;
    sc[t] = bc;
    __syncthreads();
    for (int off = 1; off < 256; off <<= 1) {
        int x = sc[t];
        int a = (t >= off) ? sc[t - off] : 0;
        __syncthreads();
        sc[t] = x + a;
        __syncthreads();
    }
    int gbase = sc[t] - bc;
    int c = cnt[t];
    bb[t] = (t < NB && c) ? (gbase + atomicAdd(&bucket_cursor[t], c)) : 0;
    __syncthreads();
#pragma unroll
    for (int j = 0; j < 8; ++j) {
        if (dsts[j] >= 0) {
            int b = dsts[j] >> 8;
            uint v = (uint)srcs[j] | ((uint)(dsts[j] & 255) << 16);
            __builtin_nontemporal_store(v, &bdata[bb[b] + rank[j]]);
        }
    }
}

// ============================================================ bucket -> CSR
#define BCAP 12800
__global__ __launch_bounds__(256) void bucket_csr_kernel(
    const uint* __restrict__ bdata, const int* __restrict__ bucket_count,
    int NB, int E, int* __restrict__ row_start, ushort* __restrict__ csr_src,
    int N)
{
    __shared__ int hist[2048];
    __shared__ int cur[2048];
    __shared__ int scn[256];
    __shared__ int sb[256];
    __shared__ ushort buf[BCAP];
    const int b = blockIdx.x;
    const int t = threadIdx.x;

    int bc = (t < NB) ? bucket_count[t] : 0;
    sb[t] = bc;
    __syncthreads();
    for (int off = 1; off < 256; off <<= 1) {
        int x = sb[t];
        int a = (t >= off) ? sb[t - off] : 0;
        __syncthreads();
        sb[t] = x + a;
        __syncthreads();
    }
    const int beg = (b > 0) ? sb[b - 1] : 0;
    const int sz = sb[b] - beg;
    if (b == 0 && t == 0) row_start[N] = E;

#pragma unroll
    for (int j = 0; j < 8; ++j) hist[t * 8 + j] = 0;
    __syncthreads();
    for (int i = t; i < sz; i += 256) {
        uint d = bdata[beg + i];
        int key = (int)((d >> 16) << 3) | (int)((d & 0xFFFFu) >> SEG_SHIFT);
        atomicAdd(&hist[key], 1);
    }
    __syncthreads();
    int local[8]; int s = 0;
#pragma unroll
    for (int j = 0; j < 8; ++j) { local[j] = hist[t * 8 + j]; s += local[j]; }
    scn[t] = s;
    __syncthreads();
    for (int off = 1; off < 256; off <<= 1) {
        int x = scn[t];
        int a = (t >= off) ? scn[t - off] : 0;
        __syncthreads();
        scn[t] = x + a;
        __syncthreads();
    }
    int run = scn[t] - s;
#pragma unroll
    for (int j = 0; j < 8; ++j) { cur[t * 8 + j] = run; run += local[j]; }
    __syncthreads();
    int node = b * 256 + t;
    if (node < N) row_start[node] = beg + cur[t << 3];
    __syncthreads();
    if (sz <= BCAP) {
        for (int i = t; i < sz; i += 256) {
            uint d = bdata[beg + i];
            int key = (int)((d >> 16) << 3) | (int)((d & 0xFFFFu) >> SEG_SHIFT);
            int pos = atomicAdd(&cur[key], 1);
            buf[pos] = (ushort)(d & 0xFFFFu);
        }
        __syncthreads();
        for (int i = t; i < sz; i += 256)
            __builtin_nontemporal_store(buf[i], &csr_src[beg + i]);
    } else {
        for (int i = t; i < sz; i += 256) {
            uint d = bdata[beg + i];
            int key = (int)((d >> 16) << 3) | (int)((d & 0xFFFFu) >> SEG_SHIFT);
            int pos = atomicAdd(&cur[key], 1);
            csr_src[beg + pos] = (ushort)(d & 0xFFFFu);
        }
    }
}

// ============================================================ agg core (computes a0..a7, sx)
static __device__ __forceinline__ void agg_core(
    const ushort* __restrict__ csr_src, const int* __restrict__ row_start,
    const float* __restrict__ alpha_s, const float* __restrict__ alpha_d,
    const uint* __restrict__ h2, int g, int l, int head,
    float& a0, float& a1, float& a2, float& a3,
    float& a4, float& a5, float& a6, float& a7, float& sx)
{
    const char* hbase = (const char*)h2 + (size_t)l * 16;
    const float ad = alpha_d[g * 4 + head];

    float e = alpha_s[g * 4 + head] + ad;
    e = e > 0.f ? e : NEG_SLOPE * e;
    float ex = __expf(e);
    uint4 q = *(const uint4*)(hbase + (uint)g * 256u);
    a0 = ex * bf_lo(q.x); a1 = ex * bf_hi(q.x);
    a2 = ex * bf_lo(q.y); a3 = ex * bf_hi(q.y);
    a4 = ex * bf_lo(q.z); a5 = ex * bf_hi(q.z);
    a6 = ex * bf_lo(q.w); a7 = ex * bf_hi(q.w);
    sx = ex;

    const int beg = row_start[g];
    const int end = row_start[g + 1];
    int k = beg;
    for (; k + 4 <= end; k += 4) {
        uint s0 = csr_src[k], s1 = csr_src[k + 1];
        uint s2 = csr_src[k + 2], s3 = csr_src[k + 3];
        uint4 q0 = *(const uint4*)(hbase + s0 * 256u);
        uint4 q1 = *(const uint4*)(hbase + s1 * 256u);
        uint4 q2 = *(const uint4*)(hbase + s2 * 256u);
        uint4 q3 = *(const uint4*)(hbase + s3 * 256u);
        float e0 = alpha_s[s0 * 4 + head] + ad;
        float e1 = alpha_s[s1 * 4 + head] + ad;
        float e2 = alpha_s[s2 * 4 + head] + ad;
        float e3 = alpha_s[s3 * 4 + head] + ad;
        e0 = e0 > 0.f ? e0 : NEG_SLOPE * e0;
        e1 = e1 > 0.f ? e1 : NEG_SLOPE * e1;
        e2 = e2 > 0.f ? e2 : NEG_SLOPE * e2;
        e3 = e3 > 0.f ? e3 : NEG_SLOPE * e3;
        float x0 = __expf(e0), x1 = __expf(e1);
        float x2 = __expf(e2), x3 = __expf(e3);
        a0 += x0 * bf_lo(q0.x) + x1 * bf_lo(q1.x) + x2 * bf_lo(q2.x) + x3 * bf_lo(q3.x);
        a1 += x0 * bf_hi(q0.x) + x1 * bf_hi(q1.x) + x2 * bf_hi(q2.x) + x3 * bf_hi(q3.x);
        a2 += x0 * bf_lo(q0.y) + x1 * bf_lo(q1.y) + x2 * bf_lo(q2.y) + x3 * bf_lo(q3.y);
        a3 += x0 * bf_hi(q0.y) + x1 * bf_hi(q1.y) + x2 * bf_hi(q2.y) + x3 * bf_hi(q3.y);
        a4 += x0 * bf_lo(q0.z) + x1 * bf_lo(q1.z) + x2 * bf_lo(q2.z) + x3 * bf_lo(q3.z);
        a5 += x0 * bf_hi(q0.z) + x1 * bf_hi(q1.z) + x2 * bf_hi(q2.z) + x3 * bf_hi(q3.z);
        a6 += x0 * bf_lo(q0.w) + x1 * bf_lo(q1.w) + x2 * bf_lo(q2.w) + x3 * bf_lo(q3.w);
        a7 += x0 * bf_hi(q0.w) + x1 * bf_hi(q1.w) + x2 * bf_hi(q2.w) + x3 * bf_hi(q3.w);
        sx += x0 + x1 + x2 + x3;
    }
    for (; k < end; ++k) {
        uint s0 = csr_src[k];
        float e0 = alpha_s[s0 * 4 + head] + ad;
        uint4 q0 = *(const uint4*)(hbase + s0 * 256u);
        e0 = e0 > 0.f ? e0 : NEG_SLOPE * e0;
        float x0 = __expf(e0);
        a0 += x0 * bf_lo(q0.x); a1 += x0 * bf_hi(q0.x);
        a2 += x0 * bf_lo(q0.y); a3 += x0 * bf_hi(q0.y);
        a4 += x0 * bf_lo(q0.z); a5 += x0 * bf_hi(q0.z);
        a6 += x0 * bf_lo(q0.w); a7 += x0 * bf_hi(q0.w);
        sx += x0;
    }
}

// ============================================================ agg + fused next-layer GEMM
// Alpha ping-pong: reads layer-l alphas, writes layer-l+1 alphas to SEPARATE
// buffers (cross-block race otherwise). h2out stores are nontemporal: the
// write-once stream must not allocate in L2 (it evicts h2in gather lines).
__global__ __launch_bounds__(256) void aggemm_kernel(
    const ushort* __restrict__ csr_src, const int* __restrict__ row_start,
    const float* __restrict__ alpha_s, const float* __restrict__ alpha_d,
    const uint* __restrict__ h2in, const float* __restrict__ b,
    const uint4* __restrict__ Wnext,
    const float* __restrict__ att_s, const float* __restrict__ att_d,
    uint* __restrict__ h2out, float* __restrict__ alpha_s_out,
    float* __restrict__ alpha_d_out, int N)
{
    __shared__ __align__(16) uint4 tile[16 * 17];   // [node][k-chunk], padded
    const int t = threadIdx.x;
    const int nodeBase = blockIdx.x * 16;
    const int gl = t >> 4;
    const int g = nodeBase + gl;
    const int l = t & 15;
    const bool active = g < N;

    uint4 o = make_uint4(0u, 0u, 0u, 0u);
    if (active) {
        float a0, a1, a2, a3, a4, a5, a6, a7, sx;
        agg_core(csr_src, row_start, alpha_s, alpha_d, h2in, g, l, l >> 2,
                 a0, a1, a2, a3, a4, a5, a6, a7, sx);
        const float inv = 1.f / (sx + EPSF);
        const float4 b0 = ((const float4*)b)[l * 2];
        const float4 b1 = ((const float4*)b)[l * 2 + 1];
        o.x = pack2(b0.x + a0 * inv, b0.y + a1 * inv);
        o.y = pack2(b0.z + a2 * inv, b0.w + a3 * inv);
        o.z = pack2(b1.x + a4 * inv, b1.y + a5 * inv);
        o.w = pack2(b1.z + a6 * inv, b1.w + a7 * inv);
    }
    tile[gl * 17 + l] = o;
    __syncthreads();

    const int w = t >> 6, lane = t & 63, q = lane >> 4, l15 = lane & 15;
    floatx4 acc0 = (floatx4){0.f, 0.f, 0.f, 0.f};
    floatx4 acc1 = (floatx4){0.f, 0.f, 0.f, 0.f};
#pragma unroll
    for (int s = 0; s < 4; ++s) {
        short8 xfr = u2s8(tile[l15 * 17 + 4 * s + q]);
        short8 wf0 = u2s8(Wnext[(4 * s + q) * 128 + 16 * (2 * w) + l15]);
        short8 wf1 = u2s8(Wnext[(4 * s + q) * 128 + 16 * (2 * w + 1) + l15]);
        acc0 = __builtin_amdgcn_mfma_f32_16x16x32_bf16(wf0, xfr, acc0, 0, 0, 0);
        acc1 = __builtin_amdgcn_mfma_f32_16x16x32_bf16(wf1, xfr, acc1, 0, 0, 0);
    }
    const int node = nodeBase + l15;
    if (node < N) {
        uint* hp = h2out + (size_t)node * 64;
        uintx2 o0, o1;
        o0.x = pack2(acc0[0], acc0[1]); o0.y = pack2(acc0[2], acc0[3]);
        o1.x = pack2(acc1[0], acc1[1]); o1.y = pack2(acc1[2], acc1[3]);
        __builtin_nontemporal_store(o0, (uintx2*)(hp + 16 * w + 2 * q));
        __builtin_nontemporal_store(o1, (uintx2*)(hp + 16 * w + 8 + 2 * q));
    }
    const float4 as0 = *(const float4*)(att_s + 32 * w + 4 * q);
    const float4 as1 = *(const float4*)(att_s + 32 * w + 16 + 4 * q);
    const float4 ad0 = *(const float4*)(att_d + 32 * w + 4 * q);
    const float4 ad1 = *(const float4*)(att_d + 32 * w + 16 + 4 * q);
    float ps = acc0[0] * as0.x + acc0[1] * as0.y + acc0[2] * as0.z + acc0[3] * as0.w
             + acc1[0] * as1.x + acc1[1] * as1.y + acc1[2] * as1.z + acc1[3] * as1.w;
    float pd = acc0[0] * ad0.x + acc0[1] * ad0.y + acc0[2] * ad0.z + acc0[3] * ad0.w
             + acc1[0] * ad1.x + acc1[1] * ad1.y + acc1[2] * ad1.z + acc1[3] * ad1.w;
    ps += __shfl_xor(ps, 16); ps += __shfl_xor(ps, 32);
    pd += __shfl_xor(pd, 16); pd += __shfl_xor(pd, 32);
    if (node < N && q == 0) {
        alpha_s_out[(size_t)node * 4 + w] = ps;
        alpha_d_out[(size_t)node * 4 + w] = pd;
    }
}

// ============================================================ final agg + MLP (fused)
__global__ __launch_bounds__(256) void aggmlp_kernel(
    const ushort* __restrict__ csr_src, const int* __restrict__ row_start,
    const float* __restrict__ alpha_s, const float* __restrict__ alpha_d,
    const uint* __restrict__ h2in, const float* __restrict__ b,
    const uint4* __restrict__ xb0, const uint4* __restrict__ W1p,
    const float* __restrict__ b1, const float* __restrict__ W2,
    const float* __restrict__ b2, float* __restrict__ out, int N)
{
    __shared__ __align__(16) uint4 tile[16 * 33];   // [node][32 chunks, pad 33]
    __shared__ float pr[32];
    const int t = threadIdx.x;
    const int nodeBase = blockIdx.x * 16;
    const int gl = t >> 4;
    const int g = nodeBase + gl;
    const int l = t & 15;

    // x0 rows -> chunks 16..31 (nontemporal read: read-once, keep L2 for h2in)
    {
        uintx4 v = (uintx4){0u, 0u, 0u, 0u};
        if (g < N)
            v = __builtin_nontemporal_load(
                (const uintx4*)(xb0 + (size_t)g * 16 + l));
        union { uintx4 x; uint4 u; } cc; cc.x = v;
        tile[gl * 33 + 16 + l] = cc.u;
    }

    uint4 o = make_uint4(0u, 0u, 0u, 0u);
    if (g < N) {
        float a0, a1, a2, a3, a4, a5, a6, a7, sx;
        agg_core(csr_src, row_start, alpha_s, alpha_d, h2in, g, l, l >> 2,
                 a0, a1, a2, a3, a4, a5, a6, a7, sx);
        const float inv = 1.f / (sx + EPSF);
        const float4 b0 = ((const float4*)b)[l * 2];
        const float4 b1v = ((const float4*)b)[l * 2 + 1];
        o.x = pack2(b0.x + a0 * inv, b0.y + a1 * inv);
        o.y = pack2(b0.z + a2 * inv, b0.w + a3 * inv);
        o.z = pack2(b1v.x + a4 * inv, b1v.y + a5 * inv);
        o.w = pack2(b1v.z + a6 * inv, b1v.w + a7 * inv);
    }
    tile[gl * 33 + l] = o;
    __syncthreads();

    const int w = t >> 6, lane = t & 63, q = lane >> 4, l15 = lane & 15;
    if (w < 2) {
        floatx4 acc = (floatx4){0.f, 0.f, 0.f, 0.f};
#pragma unroll
        for (int s = 0; s < 8; ++s) {
            short8 a = u2s8(tile[l15 * 33 + 4 * s + q]);
            short8 bb = u2s8(W1p[(4 * s + q) * 32 + 16 * w + l15]);
            acc = __builtin_amdgcn_mfma_f32_16x16x32_bf16(a, bb, acc, 0, 0, 0);
        }
        const int col = 16 * w + l15;
        const float b1c = b1[col], w2c = W2[col];
#pragma unroll
        for (int r = 0; r < 4; ++r) {
            float v = acc[r] + b1c;
            v = v > 0.f ? v : 0.f;
            float p = v * w2c;
            p += __shfl_xor(p, 1);
            p += __shfl_xor(p, 2);
            p += __shfl_xor(p, 4);
            p += __shfl_xor(p, 8);
            if (l15 == 0) pr[w * 16 + 4 * q + r] = p;
        }
    }
    __syncthreads();
    if (t < 16) {
        int node = nodeBase + t;
        if (node < N) {
            float z = pr[t] + pr[16 + t] + b2[0];
            out[node] = 1.f / (1.f + __expf(-z));
        }
    }
}

// ============================================================ launch
extern "C" void kernel_launch(void* const* d_in, const int* in_sizes, int n_in,
                              void* d_out, int out_size, void* d_ws, size_t ws_size,
                              hipStream_t stream)
{
    const float* x       = (const float*)d_in[0];
    const int*   ei      = (const int*)d_in[1];
    const float* W       = (const float*)d_in[2];
    const float* att_src = (const float*)d_in[3];
    const float* att_dst = (const float*)d_in[4];
    const float* b_conv  = (const float*)d_in[5];
    const float* W1      = (const float*)d_in[6];
    const float* b1      = (const float*)d_in[7];
    const float* W2      = (const float*)d_in[8];
    const float* b2      = (const float*)d_in[9];
    float* outp = (float*)d_out;

    const int N = in_sizes[0] / 128;
    const int E = in_sizes[1] / 2;
    const int L = in_sizes[2] / (128 * 128);
    const int NB = (N + 255) >> 8;

    char* ws = (char*)d_ws;
    uint*  h2a      = (uint*)ws;                          // N*64 uints
    uint*  h2b      = h2a + (size_t)N * 64;               // N*64 uints (ping-pong)
    uint4* xb0      = (uint4*)(h2b + (size_t)N * 64);     // N*16 uint4 (bf16 x)
    float* alphaA_s = (float*)(xb0 + (size_t)N * 16);     // N*4
    float* alphaA_d = alphaA_s + (size_t)N * 4;           // N*4
    float* alphaB_s = alphaA_d + (size_t)N * 4;           // N*4
    float* alphaB_d = alphaB_s + (size_t)N * 4;           // N*4
    uint4* Wp       = (uint4*)(alphaB_d + (size_t)N * 4); // L*2048
    uint4* W1p      = Wp + (size_t)L * 2048;              // 1024
    int* bucket_count  = (int*)(W1p + 1024);              // 256
    int* bucket_cursor = bucket_count + 256;              // 256
    int* row_start     = bucket_cursor + 256;             // N+1
    uint* bdata        = (uint*)(row_start + N + 1);      // E
    ushort* csr_src    = (ushort*)(bdata + E);            // E

    const int nbEc = (E + 2047) / 2048;
    const int nbEd = (E + 2047) / 2048;
    const int gBlocks = (N + 63) / 64;
    const int aggBlocks = (N + 15) / 16;
    const int prepItems = L * 2048 + 1024 + N * 16;
    const int nbPrep = (prepItems + 255) / 256;

    (void)hipMemsetAsync(bucket_count, 0, 512 * sizeof(int), stream);

    prep_count_kernel<<<nbPrep + nbEc, 256, 0, stream>>>(
        W, W1, x, Wp, W1p, xb0, ei, E, NB, bucket_count, L, N, nbPrep);

    dist_gemm_kernel<<<nbEd + gBlocks, 256, 0, stream>>>(
        ei, E, NB, bucket_count, bucket_cursor, bdata, nbEd,
        xb0, Wp, att_src, att_dst, h2a, alphaA_s, alphaA_d, N);

    bucket_csr_kernel<<<NB, 256, 0, stream>>>(bdata, bucket_count, NB, E,
                                              row_start, csr_src, N);

    // layer 0: read h2a/alphaA -> write h2b/alphaB
    aggemm_kernel<<<aggBlocks, 256, 0, stream>>>(
        csr_src, row_start, alphaA_s, alphaA_d, h2a,
        b_conv + 0 * 128, Wp + (size_t)1 * 2048,
        att_src + (size_t)1 * 128, att_dst + (size_t)1 * 128,
        h2b, alphaB_s, alphaB_d, N);

    // layer 1: read h2b/alphaB -> write h2a/alphaA
    aggemm_kernel<<<aggBlocks, 256, 0, stream>>>(
        csr_src, row_start, alphaB_s, alphaB_d, h2b,
        b_conv + (size_t)1 * 128, Wp + (size_t)2 * 2048,
        att_src + (size_t)2 * 128, att_dst + (size_t)2 * 128,
        h2a, alphaA_s, alphaA_d, N);

    // layer 2 + MLP fused
    aggmlp_kernel<<<aggBlocks, 256, 0, stream>>>(
        csr_src, row_start, alphaA_s, alphaA_d, h2a,
        b_conv + (size_t)2 * 128, xb0, W1p, b1, W2, b2, outp, N);
}

// Round 15
// 327.964 us; speedup vs baseline: 1.1147x; 1.1147x over previous
//
#include <hip/hip_runtime.h>

#define NEG_SLOPE 0.2f
#define EPSF 1e-16f
#define SEG_SHIFT 13   // src segment = src >> 13 (8192 rows = 2 MB of h2)

typedef unsigned int uint;
typedef unsigned short ushort;
typedef __attribute__((ext_vector_type(8))) short short8;   // 8 bf16 (4 VGPRs)
typedef __attribute__((ext_vector_type(4))) float floatx4;  // MFMA acc
typedef __attribute__((ext_vector_type(4))) uint uintx4;    // nontemporal 16B
typedef __attribute__((ext_vector_type(2))) uint uintx2;    // nontemporal 8B

// RNE float->bf16
static __device__ __forceinline__ ushort f2bf(float f) {
    uint u = __float_as_uint(f);
    return (ushort)((u + 0x7FFFu + ((u >> 16) & 1u)) >> 16);
}
static __device__ __forceinline__ uint pack2(float a, float b) {
    return (uint)f2bf(a) | ((uint)f2bf(b) << 16);
}
static __device__ __forceinline__ float bf_lo(uint p) { return __uint_as_float(p << 16); }
static __device__ __forceinline__ float bf_hi(uint p) { return __uint_as_float(p & 0xFFFF0000u); }
static __device__ __forceinline__ short8 u2s8(uint4 v) {
    union { uint4 u; short8 s; } c; c.u = v; return c.s;
}
// async global->LDS, 16B per lane, dst = wave-uniform base + lane*16
static __device__ __forceinline__ void load_lds16(const void* g, void* l) {
    __builtin_amdgcn_global_load_lds(
        (const __attribute__((address_space(1))) void*)g,
        (__attribute__((address_space(3))) void*)l, 16, 0, 0);
}

#define GA_LDS_BYTES (2048 * 16 + 16 * 65 * 16)   // sW + sX = 49408

// ============================================================ GEMM + alpha body (MFMA, transposed)
static __device__ __forceinline__ void gemm_body(
    char* smraw, const uint4* __restrict__ xb, const uint4* __restrict__ Wp,
    const float* __restrict__ att_s, const float* __restrict__ att_d,
    uint* __restrict__ h2, float* __restrict__ alpha_s,
    float* __restrict__ alpha_d, int N, int rowBase)
{
    uint4* sW = (uint4*)smraw;                 // 2048 slots (linear copy of Wp)
    uint4* sX = sW + 2048;                     // 16 chunks * 65 slots

    const int t = threadIdx.x;
    const int wb = t & ~63;

#pragma unroll
    for (int i = 0; i < 8; ++i)
        load_lds16(Wp + i * 256 + t, sW + i * 256 + wb);

#pragma unroll
    for (int i = 0; i < 4; ++i) {
        int f = t + i * 256;
        int row = f >> 4, c8 = f & 15;
        uint4 v = make_uint4(0u, 0u, 0u, 0u);
        if (rowBase + row < N) v = xb[(size_t)(rowBase + row) * 16 + c8];
        sX[c8 * 65 + row] = v;
    }
    __syncthreads();

    const int w = t >> 6, lane = t & 63, q = lane >> 4, l15 = lane & 15;
    short8 xf[4];
#pragma unroll
    for (int s = 0; s < 4; ++s)
        xf[s] = u2s8(sX[(4 * s + q) * 65 + 16 * w + l15]);

    floatx4 acc[8];
#pragma unroll
    for (int ct = 0; ct < 8; ++ct) acc[ct] = (floatx4){0.f, 0.f, 0.f, 0.f};
#pragma unroll
    for (int ct = 0; ct < 8; ++ct) {
#pragma unroll
        for (int s = 0; s < 4; ++s) {
            short8 wf = u2s8(sW[(4 * s + q) * 128 + 16 * ct + l15]);
            acc[ct] = __builtin_amdgcn_mfma_f32_16x16x32_bf16(wf, xf[s], acc[ct], 0, 0, 0);
        }
    }

    const int node = rowBase + 16 * w + l15;
    if (node < N) {
        uint2* hp = (uint2*)(h2 + (size_t)node * 64);
#pragma unroll
        for (int ct = 0; ct < 8; ++ct) {
            uint2 o;
            o.x = pack2(acc[ct][0], acc[ct][1]);
            o.y = pack2(acc[ct][2], acc[ct][3]);
            hp[4 * ct + q] = o;
        }
    }
    float ps[4], pd[4];
#pragma unroll
    for (int hd = 0; hd < 4; ++hd) {
        const float4 as0 = *(const float4*)(att_s + 32 * hd + 4 * q);
        const float4 as1 = *(const float4*)(att_s + 32 * hd + 16 + 4 * q);
        const float4 ad0 = *(const float4*)(att_d + 32 * hd + 4 * q);
        const float4 ad1 = *(const float4*)(att_d + 32 * hd + 16 + 4 * q);
        floatx4 c0 = acc[2 * hd], c1 = acc[2 * hd + 1];
        ps[hd] = c0[0] * as0.x + c0[1] * as0.y + c0[2] * as0.z + c0[3] * as0.w
               + c1[0] * as1.x + c1[1] * as1.y + c1[2] * as1.z + c1[3] * as1.w;
        pd[hd] = c0[0] * ad0.x + c0[1] * ad0.y + c0[2] * ad0.z + c0[3] * ad0.w
               + c1[0] * ad1.x + c1[1] * ad1.y + c1[2] * ad1.z + c1[3] * ad1.w;
    }
#pragma unroll
    for (int hd = 0; hd < 4; ++hd) {
        ps[hd] += __shfl_xor(ps[hd], 16);
        ps[hd] += __shfl_xor(ps[hd], 32);
        pd[hd] += __shfl_xor(pd[hd], 16);
        pd[hd] += __shfl_xor(pd[hd], 32);
    }
    if (node < N) {
        alpha_s[(size_t)node * 4 + q] = ps[q];
        alpha_d[(size_t)node * 4 + q] = pd[q];
    }
}

// ============================================================ prep + bucket count (fused)
__global__ __launch_bounds__(256) void prep_count_kernel(
    const float* __restrict__ W, const float* __restrict__ W1,
    const float* __restrict__ x, uint4* __restrict__ Wp,
    uint4* __restrict__ W1p, uint4* __restrict__ xb,
    const int* __restrict__ ei, int E, int NB,
    int* __restrict__ bucket_count, int L, int N, int nbPrep)
{
    __shared__ int cnt[256];
    if ((int)blockIdx.x >= nbPrep) {
        cnt[threadIdx.x] = 0;
        __syncthreads();
        const int base = (blockIdx.x - nbPrep) * 2048 + threadIdx.x;
#pragma unroll
        for (int j = 0; j < 8; ++j) {
            int idx = base + j * 256;
            if (idx < E) atomicAdd(&cnt[ei[E + idx] >> 8], 1);
        }
        __syncthreads();
        int c = cnt[threadIdx.x];
        if ((int)threadIdx.x < NB && c) atomicAdd(&bucket_count[threadIdx.x], c);
        return;
    }
    int id = blockIdx.x * 256 + threadIdx.x;
    const int nW = L * 2048;
    const int nX = N * 16;
    if (id < nW) {
        int l = id >> 11, s = id & 2047;
        int chunk = s >> 7, col = s & 127;
        const float* wp = W + (size_t)l * 16384 + (chunk * 8) * 128 + col;
        uint4 pk;
        pk.x = pack2(wp[0],   wp[128]);
        pk.y = pack2(wp[256], wp[384]);
        pk.z = pack2(wp[512], wp[640]);
        pk.w = pack2(wp[768], wp[896]);
        Wp[id] = pk;
    } else if (id < nW + 1024) {
        int s = id - nW;
        int chunk = s >> 5, col = s & 31;
        const float* wp = W1 + (chunk * 8) * 32 + col;
        uint4 pk;
        pk.x = pack2(wp[0],   wp[32]);
        pk.y = pack2(wp[64],  wp[96]);
        pk.z = pack2(wp[128], wp[160]);
        pk.w = pack2(wp[192], wp[224]);
        W1p[s] = pk;
    } else if (id < nW + 1024 + nX) {
        int xid = id - nW - 1024;
        int row = xid >> 4, c8 = xid & 15;
        const float4* xp = (const float4*)(x + (size_t)row * 128 + c8 * 8);
        float4 v0 = xp[0], v1 = xp[1];
        uint4 pk;
        pk.x = pack2(v0.x, v0.y); pk.y = pack2(v0.z, v0.w);
        pk.z = pack2(v1.x, v1.y); pk.w = pack2(v1.z, v1.w);
        xb[xid] = pk;
    }
}

// ============================================================ distribute + gemm l0 (grid-fused)
__global__ __launch_bounds__(256) void dist_gemm_kernel(
    const int* __restrict__ ei, int E, int NB,
    const int* __restrict__ bucket_count, int* __restrict__ bucket_cursor,
    uint* __restrict__ bdata, int nbEd,
    const uint4* __restrict__ xb, const uint4* __restrict__ Wp,
    const float* __restrict__ att_s, const float* __restrict__ att_d,
    uint* __restrict__ h2, float* __restrict__ alpha_s,
    float* __restrict__ alpha_d, int N)
{
    __shared__ __align__(16) char smraw[GA_LDS_BYTES];
    const int t = threadIdx.x;
    if ((int)blockIdx.x >= nbEd) {
        gemm_body(smraw, xb, Wp, att_s, att_d, h2, alpha_s, alpha_d, N,
                  (blockIdx.x - nbEd) * 64);
        return;
    }
    int* cnt = (int*)smraw;        // 256
    int* sc  = cnt + 256;          // 256
    int* bb  = sc + 256;           // 256
    cnt[t] = 0;
    __syncthreads();
    const int base = blockIdx.x * 2048 + t;
    int srcs[8], dsts[8], rank[8];
#pragma unroll
    for (int j = 0; j < 8; ++j) {
        int idx = base + j * 256;
        if (idx < E) {
            srcs[j] = ei[idx];
            dsts[j] = ei[E + idx];
            rank[j] = atomicAdd(&cnt[dsts[j] >> 8], 1);
        } else dsts[j] = -1;
    }
    __syncthreads();
    int bc = (t < NB) ? bucket_count[t] : 0;
    sc[t] = bc;
    __syncthreads();
    for (int off = 1; off < 256; off <<= 1) {
        int x = sc[t];
        int a = (t >= off) ? sc[t - off] : 0;
        __syncthreads();
        sc[t] = x + a;
        __syncthreads();
    }
    int gbase = sc[t] - bc;
    int c = cnt[t];
    bb[t] = (t < NB && c) ? (gbase + atomicAdd(&bucket_cursor[t], c)) : 0;
    __syncthreads();
    // plain stores: scattered 4B pattern NEEDS L2 write-combining (r14: NT
    // here caused 78 MB of partial-line writebacks, +50 µs)
#pragma unroll
    for (int j = 0; j < 8; ++j) {
        if (dsts[j] >= 0) {
            int b = dsts[j] >> 8;
            bdata[bb[b] + rank[j]] = (uint)srcs[j] | ((uint)(dsts[j] & 255) << 16);
        }
    }
}

// ============================================================ bucket -> CSR
#define BCAP 12800
__global__ __launch_bounds__(256) void bucket_csr_kernel(
    const uint* __restrict__ bdata, const int* __restrict__ bucket_count,
    int NB, int E, int* __restrict__ row_start, ushort* __restrict__ csr_src,
    int N)
{
    __shared__ int hist[2048];
    __shared__ int cur[2048];
    __shared__ int scn[256];
    __shared__ int sb[256];
    __shared__ ushort buf[BCAP];
    const int b = blockIdx.x;
    const int t = threadIdx.x;

    int bc = (t < NB) ? bucket_count[t] : 0;
    sb[t] = bc;
    __syncthreads();
    for (int off = 1; off < 256; off <<= 1) {
        int x = sb[t];
        int a = (t >= off) ? sb[t - off] : 0;
        __syncthreads();
        sb[t] = x + a;
        __syncthreads();
    }
    const int beg = (b > 0) ? sb[b - 1] : 0;
    const int sz = sb[b] - beg;
    if (b == 0 && t == 0) row_start[N] = E;

#pragma unroll
    for (int j = 0; j < 8; ++j) hist[t * 8 + j] = 0;
    __syncthreads();
    for (int i = t; i < sz; i += 256) {
        uint d = bdata[beg + i];
        int key = (int)((d >> 16) << 3) | (int)((d & 0xFFFFu) >> SEG_SHIFT);
        atomicAdd(&hist[key], 1);
    }
    __syncthreads();
    int local[8]; int s = 0;
#pragma unroll
    for (int j = 0; j < 8; ++j) { local[j] = hist[t * 8 + j]; s += local[j]; }
    scn[t] = s;
    __syncthreads();
    for (int off = 1; off < 256; off <<= 1) {
        int x = scn[t];
        int a = (t >= off) ? scn[t - off] : 0;
        __syncthreads();
        scn[t] = x + a;
        __syncthreads();
    }
    int run = scn[t] - s;
#pragma unroll
    for (int j = 0; j < 8; ++j) { cur[t * 8 + j] = run; run += local[j]; }
    __syncthreads();
    int node = b * 256 + t;
    if (node < N) row_start[node] = beg + cur[t << 3];
    __syncthreads();
    if (sz <= BCAP) {
        for (int i = t; i < sz; i += 256) {
            uint d = bdata[beg + i];
            int key = (int)((d >> 16) << 3) | (int)((d & 0xFFFFu) >> SEG_SHIFT);
            int pos = atomicAdd(&cur[key], 1);
            buf[pos] = (ushort)(d & 0xFFFFu);
        }
        __syncthreads();
        for (int i = t; i < sz; i += 256)
            __builtin_nontemporal_store(buf[i], &csr_src[beg + i]);
    } else {
        for (int i = t; i < sz; i += 256) {
            uint d = bdata[beg + i];
            int key = (int)((d >> 16) << 3) | (int)((d & 0xFFFFu) >> SEG_SHIFT);
            int pos = atomicAdd(&cur[key], 1);
            csr_src[beg + pos] = (ushort)(d & 0xFFFFu);
        }
    }
}

// ============================================================ agg core (computes a0..a7, sx)
static __device__ __forceinline__ void agg_core(
    const ushort* __restrict__ csr_src, const int* __restrict__ row_start,
    const float* __restrict__ alpha_s, const float* __restrict__ alpha_d,
    const uint* __restrict__ h2, int g, int l, int head,
    float& a0, float& a1, float& a2, float& a3,
    float& a4, float& a5, float& a6, float& a7, float& sx)
{
    const char* hbase = (const char*)h2 + (size_t)l * 16;
    const float ad = alpha_d[g * 4 + head];

    float e = alpha_s[g * 4 + head] + ad;
    e = e > 0.f ? e : NEG_SLOPE * e;
    float ex = __expf(e);
    uint4 q = *(const uint4*)(hbase + (uint)g * 256u);
    a0 = ex * bf_lo(q.x); a1 = ex * bf_hi(q.x);
    a2 = ex * bf_lo(q.y); a3 = ex * bf_hi(q.y);
    a4 = ex * bf_lo(q.z); a5 = ex * bf_hi(q.z);
    a6 = ex * bf_lo(q.w); a7 = ex * bf_hi(q.w);
    sx = ex;

    const int beg = row_start[g];
    const int end = row_start[g + 1];
    int k = beg;
    for (; k + 4 <= end; k += 4) {
        uint s0 = csr_src[k], s1 = csr_src[k + 1];
        uint s2 = csr_src[k + 2], s3 = csr_src[k + 3];
        uint4 q0 = *(const uint4*)(hbase + s0 * 256u);
        uint4 q1 = *(const uint4*)(hbase + s1 * 256u);
        uint4 q2 = *(const uint4*)(hbase + s2 * 256u);
        uint4 q3 = *(const uint4*)(hbase + s3 * 256u);
        float e0 = alpha_s[s0 * 4 + head] + ad;
        float e1 = alpha_s[s1 * 4 + head] + ad;
        float e2 = alpha_s[s2 * 4 + head] + ad;
        float e3 = alpha_s[s3 * 4 + head] + ad;
        e0 = e0 > 0.f ? e0 : NEG_SLOPE * e0;
        e1 = e1 > 0.f ? e1 : NEG_SLOPE * e1;
        e2 = e2 > 0.f ? e2 : NEG_SLOPE * e2;
        e3 = e3 > 0.f ? e3 : NEG_SLOPE * e3;
        float x0 = __expf(e0), x1 = __expf(e1);
        float x2 = __expf(e2), x3 = __expf(e3);
        a0 += x0 * bf_lo(q0.x) + x1 * bf_lo(q1.x) + x2 * bf_lo(q2.x) + x3 * bf_lo(q3.x);
        a1 += x0 * bf_hi(q0.x) + x1 * bf_hi(q1.x) + x2 * bf_hi(q2.x) + x3 * bf_hi(q3.x);
        a2 += x0 * bf_lo(q0.y) + x1 * bf_lo(q1.y) + x2 * bf_lo(q2.y) + x3 * bf_lo(q3.y);
        a3 += x0 * bf_hi(q0.y) + x1 * bf_hi(q1.y) + x2 * bf_hi(q2.y) + x3 * bf_hi(q3.y);
        a4 += x0 * bf_lo(q0.z) + x1 * bf_lo(q1.z) + x2 * bf_lo(q2.z) + x3 * bf_lo(q3.z);
        a5 += x0 * bf_hi(q0.z) + x1 * bf_hi(q1.z) + x2 * bf_hi(q2.z) + x3 * bf_hi(q3.z);
        a6 += x0 * bf_lo(q0.w) + x1 * bf_lo(q1.w) + x2 * bf_lo(q2.w) + x3 * bf_lo(q3.w);
        a7 += x0 * bf_hi(q0.w) + x1 * bf_hi(q1.w) + x2 * bf_hi(q2.w) + x3 * bf_hi(q3.w);
        sx += x0 + x1 + x2 + x3;
    }
    for (; k < end; ++k) {
        uint s0 = csr_src[k];
        float e0 = alpha_s[s0 * 4 + head] + ad;
        uint4 q0 = *(const uint4*)(hbase + s0 * 256u);
        e0 = e0 > 0.f ? e0 : NEG_SLOPE * e0;
        float x0 = __expf(e0);
        a0 += x0 * bf_lo(q0.x); a1 += x0 * bf_hi(q0.x);
        a2 += x0 * bf_lo(q0.y); a3 += x0 * bf_hi(q0.y);
        a4 += x0 * bf_lo(q0.z); a5 += x0 * bf_hi(q0.z);
        a6 += x0 * bf_lo(q0.w); a7 += x0 * bf_hi(q0.w);
        sx += x0;
    }
}

// ============================================================ agg + fused next-layer GEMM
// Alpha ping-pong (separate buffers — cross-block race otherwise). h2out
// stores nontemporal: dense write-once stream must not evict h2in L2 lines.
__global__ __launch_bounds__(256) void aggemm_kernel(
    const ushort* __restrict__ csr_src, const int* __restrict__ row_start,
    const float* __restrict__ alpha_s, const float* __restrict__ alpha_d,
    const uint* __restrict__ h2in, const float* __restrict__ b,
    const uint4* __restrict__ Wnext,
    const float* __restrict__ att_s, const float* __restrict__ att_d,
    uint* __restrict__ h2out, float* __restrict__ alpha_s_out,
    float* __restrict__ alpha_d_out, int N)
{
    __shared__ __align__(16) uint4 tile[16 * 17];   // [node][k-chunk], padded
    const int t = threadIdx.x;
    const int nodeBase = blockIdx.x * 16;
    const int gl = t >> 4;
    const int g = nodeBase + gl;
    const int l = t & 15;
    const bool active = g < N;

    uint4 o = make_uint4(0u, 0u, 0u, 0u);
    if (active) {
        float a0, a1, a2, a3, a4, a5, a6, a7, sx;
        agg_core(csr_src, row_start, alpha_s, alpha_d, h2in, g, l, l >> 2,
                 a0, a1, a2, a3, a4, a5, a6, a7, sx);
        const float inv = 1.f / (sx + EPSF);
        const float4 b0 = ((const float4*)b)[l * 2];
        const float4 b1 = ((const float4*)b)[l * 2 + 1];
        o.x = pack2(b0.x + a0 * inv, b0.y + a1 * inv);
        o.y = pack2(b0.z + a2 * inv, b0.w + a3 * inv);
        o.z = pack2(b1.x + a4 * inv, b1.y + a5 * inv);
        o.w = pack2(b1.z + a6 * inv, b1.w + a7 * inv);
    }
    tile[gl * 17 + l] = o;
    __syncthreads();

    const int w = t >> 6, lane = t & 63, q = lane >> 4, l15 = lane & 15;
    floatx4 acc0 = (floatx4){0.f, 0.f, 0.f, 0.f};
    floatx4 acc1 = (floatx4){0.f, 0.f, 0.f, 0.f};
#pragma unroll
    for (int s = 0; s < 4; ++s) {
        short8 xfr = u2s8(tile[l15 * 17 + 4 * s + q]);
        short8 wf0 = u2s8(Wnext[(4 * s + q) * 128 + 16 * (2 * w) + l15]);
        short8 wf1 = u2s8(Wnext[(4 * s + q) * 128 + 16 * (2 * w + 1) + l15]);
        acc0 = __builtin_amdgcn_mfma_f32_16x16x32_bf16(wf0, xfr, acc0, 0, 0, 0);
        acc1 = __builtin_amdgcn_mfma_f32_16x16x32_bf16(wf1, xfr, acc1, 0, 0, 0);
    }
    const int node = nodeBase + l15;
    if (node < N) {
        uint* hp = h2out + (size_t)node * 64;
        uintx2 o0, o1;
        o0.x = pack2(acc0[0], acc0[1]); o0.y = pack2(acc0[2], acc0[3]);
        o1.x = pack2(acc1[0], acc1[1]); o1.y = pack2(acc1[2], acc1[3]);
        __builtin_nontemporal_store(o0, (uintx2*)(hp + 16 * w + 2 * q));
        __builtin_nontemporal_store(o1, (uintx2*)(hp + 16 * w + 8 + 2 * q));
    }
    const float4 as0 = *(const float4*)(att_s + 32 * w + 4 * q);
    const float4 as1 = *(const float4*)(att_s + 32 * w + 16 + 4 * q);
    const float4 ad0 = *(const float4*)(att_d + 32 * w + 4 * q);
    const float4 ad1 = *(const float4*)(att_d + 32 * w + 16 + 4 * q);
    float ps = acc0[0] * as0.x + acc0[1] * as0.y + acc0[2] * as0.z + acc0[3] * as0.w
             + acc1[0] * as1.x + acc1[1] * as1.y + acc1[2] * as1.z + acc1[3] * as1.w;
    float pd = acc0[0] * ad0.x + acc0[1] * ad0.y + acc0[2] * ad0.z + acc0[3] * ad0.w
             + acc1[0] * ad1.x + acc1[1] * ad1.y + acc1[2] * ad1.z + acc1[3] * ad1.w;
    ps += __shfl_xor(ps, 16); ps += __shfl_xor(ps, 32);
    pd += __shfl_xor(pd, 16); pd += __shfl_xor(pd, 32);
    if (node < N && q == 0) {
        alpha_s_out[(size_t)node * 4 + w] = ps;
        alpha_d_out[(size_t)node * 4 + w] = pd;
    }
}

// ============================================================ final agg + MLP (fused)
__global__ __launch_bounds__(256) void aggmlp_kernel(
    const ushort* __restrict__ csr_src, const int* __restrict__ row_start,
    const float* __restrict__ alpha_s, const float* __restrict__ alpha_d,
    const uint* __restrict__ h2in, const float* __restrict__ b,
    const uint4* __restrict__ xb0, const uint4* __restrict__ W1p,
    const float* __restrict__ b1, const float* __restrict__ W2,
    const float* __restrict__ b2, float* __restrict__ out, int N)
{
    __shared__ __align__(16) uint4 tile[16 * 33];   // [node][32 chunks, pad 33]
    __shared__ float pr[32];
    const int t = threadIdx.x;
    const int nodeBase = blockIdx.x * 16;
    const int gl = t >> 4;
    const int g = nodeBase + gl;
    const int l = t & 15;

    // x0 rows -> chunks 16..31 (nontemporal read: read-once, keep L2 for h2in)
    {
        uintx4 v = (uintx4){0u, 0u, 0u, 0u};
        if (g < N)
            v = __builtin_nontemporal_load(
                (const uintx4*)(xb0 + (size_t)g * 16 + l));
        union { uintx4 x; uint4 u; } cc; cc.x = v;
        tile[gl * 33 + 16 + l] = cc.u;
    }

    uint4 o = make_uint4(0u, 0u, 0u, 0u);
    if (g < N) {
        float a0, a1, a2, a3, a4, a5, a6, a7, sx;
        agg_core(csr_src, row_start, alpha_s, alpha_d, h2in, g, l, l >> 2,
                 a0, a1, a2, a3, a4, a5, a6, a7, sx);
        const float inv = 1.f / (sx + EPSF);
        const float4 b0 = ((const float4*)b)[l * 2];
        const float4 b1v = ((const float4*)b)[l * 2 + 1];
        o.x = pack2(b0.x + a0 * inv, b0.y + a1 * inv);
        o.y = pack2(b0.z + a2 * inv, b0.w + a3 * inv);
        o.z = pack2(b1v.x + a4 * inv, b1v.y + a5 * inv);
        o.w = pack2(b1v.z + a6 * inv, b1v.w + a7 * inv);
    }
    tile[gl * 33 + l] = o;
    __syncthreads();

    const int w = t >> 6, lane = t & 63, q = lane >> 4, l15 = lane & 15;
    if (w < 2) {
        floatx4 acc = (floatx4){0.f, 0.f, 0.f, 0.f};
#pragma unroll
        for (int s = 0; s < 8; ++s) {
            short8 a = u2s8(tile[l15 * 33 + 4 * s + q]);
            short8 bb = u2s8(W1p[(4 * s + q) * 32 + 16 * w + l15]);
            acc = __builtin_amdgcn_mfma_f32_16x16x32_bf16(a, bb, acc, 0, 0, 0);
        }
        const int col = 16 * w + l15;
        const float b1c = b1[col], w2c = W2[col];
#pragma unroll
        for (int r = 0; r < 4; ++r) {
            float v = acc[r] + b1c;
            v = v > 0.f ? v : 0.f;
            float p = v * w2c;
            p += __shfl_xor(p, 1);
            p += __shfl_xor(p, 2);
            p += __shfl_xor(p, 4);
            p += __shfl_xor(p, 8);
            if (l15 == 0) pr[w * 16 + 4 * q + r] = p;
        }
    }
    __syncthreads();
    if (t < 16) {
        int node = nodeBase + t;
        if (node < N) {
            float z = pr[t] + pr[16 + t] + b2[0];
            out[node] = 1.f / (1.f + __expf(-z));
        }
    }
}

// ============================================================ launch
extern "C" void kernel_launch(void* const* d_in, const int* in_sizes, int n_in,
                              void* d_out, int out_size, void* d_ws, size_t ws_size,
                              hipStream_t stream)
{
    const float* x       = (const float*)d_in[0];
    const int*   ei      = (const int*)d_in[1];
    const float* W       = (const float*)d_in[2];
    const float* att_src = (const float*)d_in[3];
    const float* att_dst = (const float*)d_in[4];
    const float* b_conv  = (const float*)d_in[5];
    const float* W1      = (const float*)d_in[6];
    const float* b1      = (const float*)d_in[7];
    const float* W2      = (const float*)d_in[8];
    const float* b2      = (const float*)d_in[9];
    float* outp = (float*)d_out;

    const int N = in_sizes[0] / 128;
    const int E = in_sizes[1] / 2;
    const int L = in_sizes[2] / (128 * 128);
    const int NB = (N + 255) >> 8;

    char* ws = (char*)d_ws;
    uint*  h2a      = (uint*)ws;                          // N*64 uints
    uint*  h2b      = h2a + (size_t)N * 64;               // N*64 uints (ping-pong)
    uint4* xb0      = (uint4*)(h2b + (size_t)N * 64);     // N*16 uint4 (bf16 x)
    float* alphaA_s = (float*)(xb0 + (size_t)N * 16);     // N*4
    float* alphaA_d = alphaA_s + (size_t)N * 4;           // N*4
    float* alphaB_s = alphaA_d + (size_t)N * 4;           // N*4
    float* alphaB_d = alphaB_s + (size_t)N * 4;           // N*4
    uint4* Wp       = (uint4*)(alphaB_d + (size_t)N * 4); // L*2048
    uint4* W1p      = Wp + (size_t)L * 2048;              // 1024
    int* bucket_count  = (int*)(W1p + 1024);              // 256
    int* bucket_cursor = bucket_count + 256;              // 256
    int* row_start     = bucket_cursor + 256;             // N+1
    uint* bdata        = (uint*)(row_start + N + 1);      // E
    ushort* csr_src    = (ushort*)(bdata + E);            // E

    const int nbEc = (E + 2047) / 2048;
    const int nbEd = (E + 2047) / 2048;
    const int gBlocks = (N + 63) / 64;
    const int aggBlocks = (N + 15) / 16;
    const int prepItems = L * 2048 + 1024 + N * 16;
    const int nbPrep = (prepItems + 255) / 256;

    (void)hipMemsetAsync(bucket_count, 0, 512 * sizeof(int), stream);

    prep_count_kernel<<<nbPrep + nbEc, 256, 0, stream>>>(
        W, W1, x, Wp, W1p, xb0, ei, E, NB, bucket_count, L, N, nbPrep);

    dist_gemm_kernel<<<nbEd + gBlocks, 256, 0, stream>>>(
        ei, E, NB, bucket_count, bucket_cursor, bdata, nbEd,
        xb0, Wp, att_src, att_dst, h2a, alphaA_s, alphaA_d, N);

    bucket_csr_kernel<<<NB, 256, 0, stream>>>(bdata, bucket_count, NB, E,
                                              row_start, csr_src, N);

    // layer 0: read h2a/alphaA -> write h2b/alphaB
    aggemm_kernel<<<aggBlocks, 256, 0, stream>>>(
        csr_src, row_start, alphaA_s, alphaA_d, h2a,
        b_conv + 0 * 128, Wp + (size_t)1 * 2048,
        att_src + (size_t)1 * 128, att_dst + (size_t)1 * 128,
        h2b, alphaB_s, alphaB_d, N);

    // layer 1: read h2b/alphaB -> write h2a/alphaA
    aggemm_kernel<<<aggBlocks, 256, 0, stream>>>(
        csr_src, row_start, alphaB_s, alphaB_d, h2b,
        b_conv + (size_t)1 * 128, Wp + (size_t)2 * 2048,
        att_src + (size_t)2 * 128, att_dst + (size_t)2 * 128,
        h2a, alphaA_s, alphaA_d, N);

    // layer 2 + MLP fused
    aggmlp_kernel<<<aggBlocks, 256, 0, stream>>>(
        csr_src, row_start, alphaA_s, alphaA_d, h2a,
        b_conv + (size_t)2 * 128, xb0, W1p, b1, W2, b2, outp, N);
}

// Round 16
// 323.178 us; speedup vs baseline: 1.1312x; 1.0148x over previous
//
#include <hip/hip_runtime.h>

#define NEG_SLOPE 0.2f
#define EPSF 1e-16f
#define SEG_SHIFT 13   // src segment = src >> 13 (8192 rows = 2 MB of h2)

typedef unsigned int uint;
typedef unsigned short ushort;
typedef __attribute__((ext_vector_type(8))) short short8;   // 8 bf16 (4 VGPRs)
typedef __attribute__((ext_vector_type(4))) float floatx4;  // MFMA acc
typedef __attribute__((ext_vector_type(4))) uint uintx4;    // NT 16B load

// RNE float->bf16
static __device__ __forceinline__ ushort f2bf(float f) {
    uint u = __float_as_uint(f);
    return (ushort)((u + 0x7FFFu + ((u >> 16) & 1u)) >> 16);
}
static __device__ __forceinline__ uint pack2(float a, float b) {
    return (uint)f2bf(a) | ((uint)f2bf(b) << 16);
}
static __device__ __forceinline__ float bf_lo(uint p) { return __uint_as_float(p << 16); }
static __device__ __forceinline__ float bf_hi(uint p) { return __uint_as_float(p & 0xFFFF0000u); }
static __device__ __forceinline__ short8 u2s8(uint4 v) {
    union { uint4 u; short8 s; } c; c.u = v; return c.s;
}
// async global->LDS, 16B per lane, dst = wave-uniform base + lane*16
static __device__ __forceinline__ void load_lds16(const void* g, void* l) {
    __builtin_amdgcn_global_load_lds(
        (const __attribute__((address_space(1))) void*)g,
        (__attribute__((address_space(3))) void*)l, 16, 0, 0);
}

#define GA_LDS_BYTES (2048 * 16 + 16 * 65 * 16)   // sW + sX = 49408

// ============================================================ GEMM + alpha body (MFMA, transposed)
static __device__ __forceinline__ void gemm_body(
    char* smraw, const uint4* __restrict__ xb, const uint4* __restrict__ Wp,
    const float* __restrict__ att_s, const float* __restrict__ att_d,
    uint* __restrict__ h2, float* __restrict__ alpha_s,
    float* __restrict__ alpha_d, int N, int rowBase)
{
    uint4* sW = (uint4*)smraw;                 // 2048 slots (linear copy of Wp)
    uint4* sX = sW + 2048;                     // 16 chunks * 65 slots

    const int t = threadIdx.x;
    const int wb = t & ~63;

#pragma unroll
    for (int i = 0; i < 8; ++i)
        load_lds16(Wp + i * 256 + t, sW + i * 256 + wb);

#pragma unroll
    for (int i = 0; i < 4; ++i) {
        int f = t + i * 256;
        int row = f >> 4, c8 = f & 15;
        uint4 v = make_uint4(0u, 0u, 0u, 0u);
        if (rowBase + row < N) v = xb[(size_t)(rowBase + row) * 16 + c8];
        sX[c8 * 65 + row] = v;
    }
    __syncthreads();

    const int w = t >> 6, lane = t & 63, q = lane >> 4, l15 = lane & 15;
    short8 xf[4];
#pragma unroll
    for (int s = 0; s < 4; ++s)
        xf[s] = u2s8(sX[(4 * s + q) * 65 + 16 * w + l15]);

    floatx4 acc[8];
#pragma unroll
    for (int ct = 0; ct < 8; ++ct) acc[ct] = (floatx4){0.f, 0.f, 0.f, 0.f};
#pragma unroll
    for (int ct = 0; ct < 8; ++ct) {
#pragma unroll
        for (int s = 0; s < 4; ++s) {
            short8 wf = u2s8(sW[(4 * s + q) * 128 + 16 * ct + l15]);
            acc[ct] = __builtin_amdgcn_mfma_f32_16x16x32_bf16(wf, xf[s], acc[ct], 0, 0, 0);
        }
    }

    const int node = rowBase + 16 * w + l15;
    if (node < N) {
        uint2* hp = (uint2*)(h2 + (size_t)node * 64);
#pragma unroll
        for (int ct = 0; ct < 8; ++ct) {
            uint2 o;
            o.x = pack2(acc[ct][0], acc[ct][1]);
            o.y = pack2(acc[ct][2], acc[ct][3]);
            hp[4 * ct + q] = o;
        }
    }
    float ps[4], pd[4];
#pragma unroll
    for (int hd = 0; hd < 4; ++hd) {
        const float4 as0 = *(const float4*)(att_s + 32 * hd + 4 * q);
        const float4 as1 = *(const float4*)(att_s + 32 * hd + 16 + 4 * q);
        const float4 ad0 = *(const float4*)(att_d + 32 * hd + 4 * q);
        const float4 ad1 = *(const float4*)(att_d + 32 * hd + 16 + 4 * q);
        floatx4 c0 = acc[2 * hd], c1 = acc[2 * hd + 1];
        ps[hd] = c0[0] * as0.x + c0[1] * as0.y + c0[2] * as0.z + c0[3] * as0.w
               + c1[0] * as1.x + c1[1] * as1.y + c1[2] * as1.z + c1[3] * as1.w;
        pd[hd] = c0[0] * ad0.x + c0[1] * ad0.y + c0[2] * ad0.z + c0[3] * ad0.w
               + c1[0] * ad1.x + c1[1] * ad1.y + c1[2] * ad1.z + c1[3] * ad1.w;
    }
#pragma unroll
    for (int hd = 0; hd < 4; ++hd) {
        ps[hd] += __shfl_xor(ps[hd], 16);
        ps[hd] += __shfl_xor(ps[hd], 32);
        pd[hd] += __shfl_xor(pd[hd], 16);
        pd[hd] += __shfl_xor(pd[hd], 32);
    }
    if (node < N) {
        alpha_s[(size_t)node * 4 + q] = ps[q];
        alpha_d[(size_t)node * 4 + q] = pd[q];
    }
}

// ============================================================ prep + bucket count (fused)
__global__ __launch_bounds__(256) void prep_count_kernel(
    const float* __restrict__ W, const float* __restrict__ W1,
    const float* __restrict__ x, uint4* __restrict__ Wp,
    uint4* __restrict__ W1p, uint4* __restrict__ xb,
    const int* __restrict__ ei, int E, int NB,
    int* __restrict__ bucket_count, int L, int N, int nbPrep)
{
    __shared__ int cnt[256];
    if ((int)blockIdx.x >= nbPrep) {
        cnt[threadIdx.x] = 0;
        __syncthreads();
        const int base = (blockIdx.x - nbPrep) * 2048 + threadIdx.x;
#pragma unroll
        for (int j = 0; j < 8; ++j) {
            int idx = base + j * 256;
            if (idx < E) atomicAdd(&cnt[ei[E + idx] >> 8], 1);
        }
        __syncthreads();
        int c = cnt[threadIdx.x];
        if ((int)threadIdx.x < NB && c) atomicAdd(&bucket_count[threadIdx.x], c);
        return;
    }
    int id = blockIdx.x * 256 + threadIdx.x;
    const int nW = L * 2048;
    const int nX = N * 16;
    if (id < nW) {
        int l = id >> 11, s = id & 2047;
        int chunk = s >> 7, col = s & 127;
        const float* wp = W + (size_t)l * 16384 + (chunk * 8) * 128 + col;
        uint4 pk;
        pk.x = pack2(wp[0],   wp[128]);
        pk.y = pack2(wp[256], wp[384]);
        pk.z = pack2(wp[512], wp[640]);
        pk.w = pack2(wp[768], wp[896]);
        Wp[id] = pk;
    } else if (id < nW + 1024) {
        int s = id - nW;
        int chunk = s >> 5, col = s & 31;
        const float* wp = W1 + (chunk * 8) * 32 + col;
        uint4 pk;
        pk.x = pack2(wp[0],   wp[32]);
        pk.y = pack2(wp[64],  wp[96]);
        pk.z = pack2(wp[128], wp[160]);
        pk.w = pack2(wp[192], wp[224]);
        W1p[s] = pk;
    } else if (id < nW + 1024 + nX) {
        int xid = id - nW - 1024;
        int row = xid >> 4, c8 = xid & 15;
        const float4* xp = (const float4*)(x + (size_t)row * 128 + c8 * 8);
        float4 v0 = xp[0], v1 = xp[1];
        uint4 pk;
        pk.x = pack2(v0.x, v0.y); pk.y = pack2(v0.z, v0.w);
        pk.z = pack2(v1.x, v1.y); pk.w = pack2(v1.z, v1.w);
        xb[xid] = pk;
    }
}

// ============================================================ distribute (standalone)
__global__ __launch_bounds__(256) void dist_kernel(
    const int* __restrict__ ei, int E, int NB,
    const int* __restrict__ bucket_count, int* __restrict__ bucket_cursor,
    uint* __restrict__ bdata)
{
    __shared__ int cnt[256];
    __shared__ int sc[256];
    __shared__ int bb[256];
    const int t = threadIdx.x;
    cnt[t] = 0;
    __syncthreads();
    const int base = blockIdx.x * 2048 + t;
    int srcs[8], dsts[8], rank[8];
#pragma unroll
    for (int j = 0; j < 8; ++j) {
        int idx = base + j * 256;
        if (idx < E) {
            srcs[j] = ei[idx];
            dsts[j] = ei[E + idx];
            rank[j] = atomicAdd(&cnt[dsts[j] >> 8], 1);
        } else dsts[j] = -1;
    }
    __syncthreads();
    int bc = (t < NB) ? bucket_count[t] : 0;
    sc[t] = bc;
    __syncthreads();
    for (int off = 1; off < 256; off <<= 1) {
        int x = sc[t];
        int a = (t >= off) ? sc[t - off] : 0;
        __syncthreads();
        sc[t] = x + a;
        __syncthreads();
    }
    int gbase = sc[t] - bc;
    int c = cnt[t];
    bb[t] = (t < NB && c) ? (gbase + atomicAdd(&bucket_cursor[t], c)) : 0;
    __syncthreads();
    // plain stores: scattered 4B pattern NEEDS L2 write-combining (r14: NT
    // here caused 78 MB of partial-line writebacks, +50 µs)
#pragma unroll
    for (int j = 0; j < 8; ++j) {
        if (dsts[j] >= 0) {
            int b = dsts[j] >> 8;
            bdata[bb[b] + rank[j]] = (uint)srcs[j] | ((uint)(dsts[j] & 255) << 16);
        }
    }
}

// ============================================================ bucket->CSR + gemm l0 (grid-fused)
// Blocks [0,NB): per-bucket LDS sort -> csr_src. Blocks [NB,..): gemm layer 0.
// (bucket_csr needs ALL of distribute -> kernel boundary; gemm l0 independent
// of csr, so its 782 blocks hide the 196 long csr blocks.)
#define BCAP 12800
__global__ __launch_bounds__(256) void csr_gemm_kernel(
    const uint* __restrict__ bdata, const int* __restrict__ bucket_count,
    int NB, int E, int* __restrict__ row_start, ushort* __restrict__ csr_src,
    const uint4* __restrict__ xb, const uint4* __restrict__ Wp,
    const float* __restrict__ att_s, const float* __restrict__ att_d,
    uint* __restrict__ h2, float* __restrict__ alpha_s,
    float* __restrict__ alpha_d, int N)
{
    __shared__ __align__(16) char smraw[GA_LDS_BYTES];   // 49408 B, overlaid
    const int t = threadIdx.x;
    if ((int)blockIdx.x >= NB) {
        gemm_body(smraw, xb, Wp, att_s, att_d, h2, alpha_s, alpha_d, N,
                  (blockIdx.x - NB) * 64);
        return;
    }
    int* hist = (int*)smraw;                 // 2048
    int* cur  = hist + 2048;                 // 2048
    int* scn  = cur + 2048;                  // 256
    int* sb   = scn + 256;                   // 256
    ushort* buf = (ushort*)(sb + 256);       // BCAP (25600 B) -> total 44032
    const int b = blockIdx.x;

    int bc = (t < NB) ? bucket_count[t] : 0;
    sb[t] = bc;
    __syncthreads();
    for (int off = 1; off < 256; off <<= 1) {
        int x = sb[t];
        int a = (t >= off) ? sb[t - off] : 0;
        __syncthreads();
        sb[t] = x + a;
        __syncthreads();
    }
    const int beg = (b > 0) ? sb[b - 1] : 0;
    const int sz = sb[b] - beg;
    if (b == 0 && t == 0) row_start[N] = E;

#pragma unroll
    for (int j = 0; j < 8; ++j) hist[t * 8 + j] = 0;
    __syncthreads();
    for (int i = t; i < sz; i += 256) {
        uint d = bdata[beg + i];
        int key = (int)((d >> 16) << 3) | (int)((d & 0xFFFFu) >> SEG_SHIFT);
        atomicAdd(&hist[key], 1);
    }
    __syncthreads();
    int local[8]; int s = 0;
#pragma unroll
    for (int j = 0; j < 8; ++j) { local[j] = hist[t * 8 + j]; s += local[j]; }
    scn[t] = s;
    __syncthreads();
    for (int off = 1; off < 256; off <<= 1) {
        int x = scn[t];
        int a = (t >= off) ? scn[t - off] : 0;
        __syncthreads();
        scn[t] = x + a;
        __syncthreads();
    }
    int run = scn[t] - s;
#pragma unroll
    for (int j = 0; j < 8; ++j) { cur[t * 8 + j] = run; run += local[j]; }
    __syncthreads();
    int node = b * 256 + t;
    if (node < N) row_start[node] = beg + cur[t << 3];
    __syncthreads();
    if (sz <= BCAP) {
        for (int i = t; i < sz; i += 256) {
            uint d = bdata[beg + i];
            int key = (int)((d >> 16) << 3) | (int)((d & 0xFFFFu) >> SEG_SHIFT);
            int pos = atomicAdd(&cur[key], 1);
            buf[pos] = (ushort)(d & 0xFFFFu);
        }
        __syncthreads();
        for (int i = t; i < sz; i += 256)
            __builtin_nontemporal_store(buf[i], &csr_src[beg + i]);
    } else {
        for (int i = t; i < sz; i += 256) {
            uint d = bdata[beg + i];
            int key = (int)((d >> 16) << 3) | (int)((d & 0xFFFFu) >> SEG_SHIFT);
            int pos = atomicAdd(&cur[key], 1);
            csr_src[beg + pos] = (ushort)(d & 0xFFFFu);
        }
    }
}

// ============================================================ agg core (computes a0..a7, sx)
static __device__ __forceinline__ void agg_core(
    const ushort* __restrict__ csr_src, const int* __restrict__ row_start,
    const float* __restrict__ alpha_s, const float* __restrict__ alpha_d,
    const uint* __restrict__ h2, int g, int l, int head,
    float& a0, float& a1, float& a2, float& a3,
    float& a4, float& a5, float& a6, float& a7, float& sx)
{
    const char* hbase = (const char*)h2 + (size_t)l * 16;
    const float ad = alpha_d[g * 4 + head];

    float e = alpha_s[g * 4 + head] + ad;
    e = e > 0.f ? e : NEG_SLOPE * e;
    float ex = __expf(e);
    uint4 q = *(const uint4*)(hbase + (uint)g * 256u);
    a0 = ex * bf_lo(q.x); a1 = ex * bf_hi(q.x);
    a2 = ex * bf_lo(q.y); a3 = ex * bf_hi(q.y);
    a4 = ex * bf_lo(q.z); a5 = ex * bf_hi(q.z);
    a6 = ex * bf_lo(q.w); a7 = ex * bf_hi(q.w);
    sx = ex;

    const int beg = row_start[g];
    const int end = row_start[g + 1];
    int k = beg;
    for (; k + 4 <= end; k += 4) {
        uint s0 = csr_src[k], s1 = csr_src[k + 1];
        uint s2 = csr_src[k + 2], s3 = csr_src[k + 3];
        uint4 q0 = *(const uint4*)(hbase + s0 * 256u);
        uint4 q1 = *(const uint4*)(hbase + s1 * 256u);
        uint4 q2 = *(const uint4*)(hbase + s2 * 256u);
        uint4 q3 = *(const uint4*)(hbase + s3 * 256u);
        float e0 = alpha_s[s0 * 4 + head] + ad;
        float e1 = alpha_s[s1 * 4 + head] + ad;
        float e2 = alpha_s[s2 * 4 + head] + ad;
        float e3 = alpha_s[s3 * 4 + head] + ad;
        e0 = e0 > 0.f ? e0 : NEG_SLOPE * e0;
        e1 = e1 > 0.f ? e1 : NEG_SLOPE * e1;
        e2 = e2 > 0.f ? e2 : NEG_SLOPE * e2;
        e3 = e3 > 0.f ? e3 : NEG_SLOPE * e3;
        float x0 = __expf(e0), x1 = __expf(e1);
        float x2 = __expf(e2), x3 = __expf(e3);
        a0 += x0 * bf_lo(q0.x) + x1 * bf_lo(q1.x) + x2 * bf_lo(q2.x) + x3 * bf_lo(q3.x);
        a1 += x0 * bf_hi(q0.x) + x1 * bf_hi(q1.x) + x2 * bf_hi(q2.x) + x3 * bf_hi(q3.x);
        a2 += x0 * bf_lo(q0.y) + x1 * bf_lo(q1.y) + x2 * bf_lo(q2.y) + x3 * bf_lo(q3.y);
        a3 += x0 * bf_hi(q0.y) + x1 * bf_hi(q1.y) + x2 * bf_hi(q2.y) + x3 * bf_hi(q3.y);
        a4 += x0 * bf_lo(q0.z) + x1 * bf_lo(q1.z) + x2 * bf_lo(q2.z) + x3 * bf_lo(q3.z);
        a5 += x0 * bf_hi(q0.z) + x1 * bf_hi(q1.z) + x2 * bf_hi(q2.z) + x3 * bf_hi(q3.z);
        a6 += x0 * bf_lo(q0.w) + x1 * bf_lo(q1.w) + x2 * bf_lo(q2.w) + x3 * bf_lo(q3.w);
        a7 += x0 * bf_hi(q0.w) + x1 * bf_hi(q1.w) + x2 * bf_hi(q2.w) + x3 * bf_hi(q3.w);
        sx += x0 + x1 + x2 + x3;
    }
    for (; k < end; ++k) {
        uint s0 = csr_src[k];
        float e0 = alpha_s[s0 * 4 + head] + ad;
        uint4 q0 = *(const uint4*)(hbase + s0 * 256u);
        e0 = e0 > 0.f ? e0 : NEG_SLOPE * e0;
        float x0 = __expf(e0);
        a0 += x0 * bf_lo(q0.x); a1 += x0 * bf_hi(q0.x);
        a2 += x0 * bf_lo(q0.y); a3 += x0 * bf_hi(q0.y);
        a4 += x0 * bf_lo(q0.z); a5 += x0 * bf_hi(q0.z);
        a6 += x0 * bf_lo(q0.w); a7 += x0 * bf_hi(q0.w);
        sx += x0;
    }
}

// ============================================================ agg + fused next-layer GEMM
// Alpha ping-pong (separate buffers — cross-block race otherwise). h2out:
// plain stores (r15: NT 8B stores from 4 different waves fragment lines,
// WRITE 14->21 MB; L2 write-combining wins here).
__global__ __launch_bounds__(256) void aggemm_kernel(
    const ushort* __restrict__ csr_src, const int* __restrict__ row_start,
    const float* __restrict__ alpha_s, const float* __restrict__ alpha_d,
    const uint* __restrict__ h2in, const float* __restrict__ b,
    const uint4* __restrict__ Wnext,
    const float* __restrict__ att_s, const float* __restrict__ att_d,
    uint* __restrict__ h2out, float* __restrict__ alpha_s_out,
    float* __restrict__ alpha_d_out, int N)
{
    __shared__ __align__(16) uint4 tile[16 * 17];   // [node][k-chunk], padded
    const int t = threadIdx.x;
    const int nodeBase = blockIdx.x * 16;
    const int gl = t >> 4;
    const int g = nodeBase + gl;
    const int l = t & 15;
    const bool active = g < N;

    uint4 o = make_uint4(0u, 0u, 0u, 0u);
    if (active) {
        float a0, a1, a2, a3, a4, a5, a6, a7, sx;
        agg_core(csr_src, row_start, alpha_s, alpha_d, h2in, g, l, l >> 2,
                 a0, a1, a2, a3, a4, a5, a6, a7, sx);
        const float inv = 1.f / (sx + EPSF);
        const float4 b0 = ((const float4*)b)[l * 2];
        const float4 b1 = ((const float4*)b)[l * 2 + 1];
        o.x = pack2(b0.x + a0 * inv, b0.y + a1 * inv);
        o.y = pack2(b0.z + a2 * inv, b0.w + a3 * inv);
        o.z = pack2(b1.x + a4 * inv, b1.y + a5 * inv);
        o.w = pack2(b1.z + a6 * inv, b1.w + a7 * inv);
    }
    tile[gl * 17 + l] = o;
    __syncthreads();

    const int w = t >> 6, lane = t & 63, q = lane >> 4, l15 = lane & 15;
    floatx4 acc0 = (floatx4){0.f, 0.f, 0.f, 0.f};
    floatx4 acc1 = (floatx4){0.f, 0.f, 0.f, 0.f};
#pragma unroll
    for (int s = 0; s < 4; ++s) {
        short8 xfr = u2s8(tile[l15 * 17 + 4 * s + q]);
        short8 wf0 = u2s8(Wnext[(4 * s + q) * 128 + 16 * (2 * w) + l15]);
        short8 wf1 = u2s8(Wnext[(4 * s + q) * 128 + 16 * (2 * w + 1) + l15]);
        acc0 = __builtin_amdgcn_mfma_f32_16x16x32_bf16(wf0, xfr, acc0, 0, 0, 0);
        acc1 = __builtin_amdgcn_mfma_f32_16x16x32_bf16(wf1, xfr, acc1, 0, 0, 0);
    }
    const int node = nodeBase + l15;
    if (node < N) {
        uint2* hp = (uint2*)(h2out + (size_t)node * 64);
        uint2 o0, o1;
        o0.x = pack2(acc0[0], acc0[1]); o0.y = pack2(acc0[2], acc0[3]);
        o1.x = pack2(acc1[0], acc1[1]); o1.y = pack2(acc1[2], acc1[3]);
        hp[8 * w + q] = o0;
        hp[8 * w + 4 + q] = o1;
    }
    const float4 as0 = *(const float4*)(att_s + 32 * w + 4 * q);
    const float4 as1 = *(const float4*)(att_s + 32 * w + 16 + 4 * q);
    const float4 ad0 = *(const float4*)(att_d + 32 * w + 4 * q);
    const float4 ad1 = *(const float4*)(att_d + 32 * w + 16 + 4 * q);
    float ps = acc0[0] * as0.x + acc0[1] * as0.y + acc0[2] * as0.z + acc0[3] * as0.w
             + acc1[0] * as1.x + acc1[1] * as1.y + acc1[2] * as1.z + acc1[3] * as1.w;
    float pd = acc0[0] * ad0.x + acc0[1] * ad0.y + acc0[2] * ad0.z + acc0[3] * ad0.w
             + acc1[0] * ad1.x + acc1[1] * ad1.y + acc1[2] * ad1.z + acc1[3] * ad1.w;
    ps += __shfl_xor(ps, 16); ps += __shfl_xor(ps, 32);
    pd += __shfl_xor(pd, 16); pd += __shfl_xor(pd, 32);
    if (node < N && q == 0) {
        alpha_s_out[(size_t)node * 4 + w] = ps;
        alpha_d_out[(size_t)node * 4 + w] = pd;
    }
}

// ============================================================ final agg + MLP (fused)
__global__ __launch_bounds__(256) void aggmlp_kernel(
    const ushort* __restrict__ csr_src, const int* __restrict__ row_start,
    const float* __restrict__ alpha_s, const float* __restrict__ alpha_d,
    const uint* __restrict__ h2in, const float* __restrict__ b,
    const uint4* __restrict__ xb0, const uint4* __restrict__ W1p,
    const float* __restrict__ b1, const float* __restrict__ W2,
    const float* __restrict__ b2, float* __restrict__ out, int N)
{
    __shared__ __align__(16) uint4 tile[16 * 33];   // [node][32 chunks, pad 33]
    __shared__ float pr[32];
    const int t = threadIdx.x;
    const int nodeBase = blockIdx.x * 16;
    const int gl = t >> 4;
    const int g = nodeBase + gl;
    const int l = t & 15;

    // x0 rows -> chunks 16..31 (nontemporal read: read-once, keep L2 for h2in)
    {
        uintx4 v = (uintx4){0u, 0u, 0u, 0u};
        if (g < N)
            v = __builtin_nontemporal_load(
                (const uintx4*)(xb0 + (size_t)g * 16 + l));
        union { uintx4 x; uint4 u; } cc; cc.x = v;
        tile[gl * 33 + 16 + l] = cc.u;
    }

    uint4 o = make_uint4(0u, 0u, 0u, 0u);
    if (g < N) {
        float a0, a1, a2, a3, a4, a5, a6, a7, sx;
        agg_core(csr_src, row_start, alpha_s, alpha_d, h2in, g, l, l >> 2,
                 a0, a1, a2, a3, a4, a5, a6, a7, sx);
        const float inv = 1.f / (sx + EPSF);
        const float4 b0 = ((const float4*)b)[l * 2];
        const float4 b1v = ((const float4*)b)[l * 2 + 1];
        o.x = pack2(b0.x + a0 * inv, b0.y + a1 * inv);
        o.y = pack2(b0.z + a2 * inv, b0.w + a3 * inv);
        o.z = pack2(b1v.x + a4 * inv, b1v.y + a5 * inv);
        o.w = pack2(b1v.z + a6 * inv, b1v.w + a7 * inv);
    }
    tile[gl * 33 + l] = o;
    __syncthreads();

    const int w = t >> 6, lane = t & 63, q = lane >> 4, l15 = lane & 15;
    if (w < 2) {
        floatx4 acc = (floatx4){0.f, 0.f, 0.f, 0.f};
#pragma unroll
        for (int s = 0; s < 8; ++s) {
            short8 a = u2s8(tile[l15 * 33 + 4 * s + q]);
            short8 bb = u2s8(W1p[(4 * s + q) * 32 + 16 * w + l15]);
            acc = __builtin_amdgcn_mfma_f32_16x16x32_bf16(a, bb, acc, 0, 0, 0);
        }
        const int col = 16 * w + l15;
        const float b1c = b1[col], w2c = W2[col];
#pragma unroll
        for (int r = 0; r < 4; ++r) {
            float v = acc[r] + b1c;
            v = v > 0.f ? v : 0.f;
            float p = v * w2c;
            p += __shfl_xor(p, 1);
            p += __shfl_xor(p, 2);
            p += __shfl_xor(p, 4);
            p += __shfl_xor(p, 8);
            if (l15 == 0) pr[w * 16 + 4 * q + r] = p;
        }
    }
    __syncthreads();
    if (t < 16) {
        int node = nodeBase + t;
        if (node < N) {
            float z = pr[t] + pr[16 + t] + b2[0];
            out[node] = 1.f / (1.f + __expf(-z));
        }
    }
}

// ============================================================ launch
extern "C" void kernel_launch(void* const* d_in, const int* in_sizes, int n_in,
                              void* d_out, int out_size, void* d_ws, size_t ws_size,
                              hipStream_t stream)
{
    const float* x       = (const float*)d_in[0];
    const int*   ei      = (const int*)d_in[1];
    const float* W       = (const float*)d_in[2];
    const float* att_src = (const float*)d_in[3];
    const float* att_dst = (const float*)d_in[4];
    const float* b_conv  = (const float*)d_in[5];
    const float* W1      = (const float*)d_in[6];
    const float* b1      = (const float*)d_in[7];
    const float* W2      = (const float*)d_in[8];
    const float* b2      = (const float*)d_in[9];
    float* outp = (float*)d_out;

    const int N = in_sizes[0] / 128;
    const int E = in_sizes[1] / 2;
    const int L = in_sizes[2] / (128 * 128);
    const int NB = (N + 255) >> 8;

    char* ws = (char*)d_ws;
    uint*  h2a      = (uint*)ws;                          // N*64 uints
    uint*  h2b      = h2a + (size_t)N * 64;               // N*64 uints (ping-pong)
    uint4* xb0      = (uint4*)(h2b + (size_t)N * 64);     // N*16 uint4 (bf16 x)
    float* alphaA_s = (float*)(xb0 + (size_t)N * 16);     // N*4
    float* alphaA_d = alphaA_s + (size_t)N * 4;           // N*4
    float* alphaB_s = alphaA_d + (size_t)N * 4;           // N*4
    float* alphaB_d = alphaB_s + (size_t)N * 4;           // N*4
    uint4* Wp       = (uint4*)(alphaB_d + (size_t)N * 4); // L*2048
    uint4* W1p      = Wp + (size_t)L * 2048;              // 1024
    int* bucket_count  = (int*)(W1p + 1024);              // 256
    int* bucket_cursor = bucket_count + 256;              // 256
    int* row_start     = bucket_cursor + 256;             // N+1
    uint* bdata        = (uint*)(row_start + N + 1);      // E
    ushort* csr_src    = (ushort*)(bdata + E);            // E

    const int nbE = (E + 2047) / 2048;
    const int gBlocks = (N + 63) / 64;
    const int aggBlocks = (N + 15) / 16;
    const int prepItems = L * 2048 + 1024 + N * 16;
    const int nbPrep = (prepItems + 255) / 256;

    (void)hipMemsetAsync(bucket_count, 0, 512 * sizeof(int), stream);

    prep_count_kernel<<<nbPrep + nbE, 256, 0, stream>>>(
        W, W1, x, Wp, W1p, xb0, ei, E, NB, bucket_count, L, N, nbPrep);

    dist_kernel<<<nbE, 256, 0, stream>>>(ei, E, NB, bucket_count,
                                         bucket_cursor, bdata);

    // bucket->CSR overlapped with gemm layer 0
    csr_gemm_kernel<<<NB + gBlocks, 256, 0, stream>>>(
        bdata, bucket_count, NB, E, row_start, csr_src,
        xb0, Wp, att_src, att_dst, h2a, alphaA_s, alphaA_d, N);

    // layer 0: read h2a/alphaA -> write h2b/alphaB
    aggemm_kernel<<<aggBlocks, 256, 0, stream>>>(
        csr_src, row_start, alphaA_s, alphaA_d, h2a,
        b_conv + 0 * 128, Wp + (size_t)1 * 2048,
        att_src + (size_t)1 * 128, att_dst + (size_t)1 * 128,
        h2b, alphaB_s, alphaB_d, N);

    // layer 1: read h2b/alphaB -> write h2a/alphaA
    aggemm_kernel<<<aggBlocks, 256, 0, stream>>>(
        csr_src, row_start, alphaB_s, alphaB_d, h2b,
        b_conv + (size_t)1 * 128, Wp + (size_t)2 * 2048,
        att_src + (size_t)2 * 128, att_dst + (size_t)2 * 128,
        h2a, alphaA_s, alphaA_d, N);

    // layer 2 + MLP fused
    aggmlp_kernel<<<aggBlocks, 256, 0, stream>>>(
        csr_src, row_start, alphaA_s, alphaA_d, h2a,
        b_conv + (size_t)2 * 128, xb0, W1p, b1, W2, b2, outp, N);
}

// Round 17
// 315.790 us; speedup vs baseline: 1.1577x; 1.0234x over previous
//
#include <hip/hip_runtime.h>

#define NEG_SLOPE 0.2f
#define EPSF 1e-16f
#define SEG_SHIFT 13   // src segment = src >> 13 (8192 rows = 2 MB of h2)

typedef unsigned int uint;
typedef unsigned short ushort;
typedef __attribute__((ext_vector_type(8))) short short8;   // 8 bf16 (4 VGPRs)
typedef __attribute__((ext_vector_type(4))) float floatx4;  // MFMA acc
typedef __attribute__((ext_vector_type(4))) uint uintx4;    // NT 16B load

// RNE float->bf16
static __device__ __forceinline__ ushort f2bf(float f) {
    uint u = __float_as_uint(f);
    return (ushort)((u + 0x7FFFu + ((u >> 16) & 1u)) >> 16);
}
static __device__ __forceinline__ uint pack2(float a, float b) {
    return (uint)f2bf(a) | ((uint)f2bf(b) << 16);
}
static __device__ __forceinline__ float bf_lo(uint p) { return __uint_as_float(p << 16); }
static __device__ __forceinline__ float bf_hi(uint p) { return __uint_as_float(p & 0xFFFF0000u); }
static __device__ __forceinline__ short8 u2s8(uint4 v) {
    union { uint4 u; short8 s; } c; c.u = v; return c.s;
}
// async global->LDS, 16B per lane, dst = wave-uniform base + lane*16
static __device__ __forceinline__ void load_lds16(const void* g, void* l) {
    __builtin_amdgcn_global_load_lds(
        (const __attribute__((address_space(1))) void*)g,
        (__attribute__((address_space(3))) void*)l, 16, 0, 0);
}

#define GA_LDS_BYTES (2048 * 16 + 16 * 65 * 16)   // sW + sX = 49408

// ============================================================ GEMM + alpha body (MFMA, transposed)
// h2 output staged through LDS (padded, then coalesced uint4 stores = full
// 64B lines) — direct 8B stores at 256B stride write-allocate in L2 (fetch!).
static __device__ __forceinline__ void gemm_body(
    char* smraw, const uint4* __restrict__ xb, const uint4* __restrict__ Wp,
    const float* __restrict__ att_s, const float* __restrict__ att_d,
    uint* __restrict__ h2, float* __restrict__ alpha_s,
    float* __restrict__ alpha_d, int N, int rowBase)
{
    uint4* sW = (uint4*)smraw;                 // 2048 slots (linear copy of Wp)
    uint4* sX = sW + 2048;                     // 16 chunks * 65 slots
    uint* stg = (uint*)sX;                     // reused: 64 rows * 65 uints

    const int t = threadIdx.x;
    const int wb = t & ~63;

#pragma unroll
    for (int i = 0; i < 8; ++i)
        load_lds16(Wp + i * 256 + t, sW + i * 256 + wb);

#pragma unroll
    for (int i = 0; i < 4; ++i) {
        int f = t + i * 256;
        int row = f >> 4, c8 = f & 15;
        uint4 v = make_uint4(0u, 0u, 0u, 0u);
        if (rowBase + row < N) v = xb[(size_t)(rowBase + row) * 16 + c8];
        sX[c8 * 65 + row] = v;
    }
    __syncthreads();

    const int w = t >> 6, lane = t & 63, q = lane >> 4, l15 = lane & 15;
    short8 xf[4];
#pragma unroll
    for (int s = 0; s < 4; ++s)
        xf[s] = u2s8(sX[(4 * s + q) * 65 + 16 * w + l15]);

    floatx4 acc[8];
#pragma unroll
    for (int ct = 0; ct < 8; ++ct) acc[ct] = (floatx4){0.f, 0.f, 0.f, 0.f};
#pragma unroll
    for (int ct = 0; ct < 8; ++ct) {
#pragma unroll
        for (int s = 0; s < 4; ++s) {
            short8 wf = u2s8(sW[(4 * s + q) * 128 + 16 * ct + l15]);
            acc[ct] = __builtin_amdgcn_mfma_f32_16x16x32_bf16(wf, xf[s], acc[ct], 0, 0, 0);
        }
    }
    __syncthreads();   // all sX reads done; safe to overwrite with staging

    // stage: node-local row stride 65 uints (pad -> ~2-way banks, free)
    {
        const int nl = 16 * w + l15;
#pragma unroll
        for (int ct = 0; ct < 8; ++ct) {
            uint2 o;
            o.x = pack2(acc[ct][0], acc[ct][1]);
            o.y = pack2(acc[ct][2], acc[ct][3]);
            *(uint2*)(stg + nl * 65 + 8 * ct + 2 * q) = o;
        }
    }
    __syncthreads();

    // coalesced copy-out: full 64B lines, no write-allocate
#pragma unroll
    for (int i = 0; i < 4; ++i) {
        int f = t + i * 256;
        int nl = f >> 4, c8 = f & 15;
        if (rowBase + nl < N)
            ((uint4*)(h2 + (size_t)(rowBase + nl) * 64))[c8] =
                *(const uint4*)(stg + nl * 65 + 4 * c8);
    }

    float ps[4], pd[4];
#pragma unroll
    for (int hd = 0; hd < 4; ++hd) {
        const float4 as0 = *(const float4*)(att_s + 32 * hd + 4 * q);
        const float4 as1 = *(const float4*)(att_s + 32 * hd + 16 + 4 * q);
        const float4 ad0 = *(const float4*)(att_d + 32 * hd + 4 * q);
        const float4 ad1 = *(const float4*)(att_d + 32 * hd + 16 + 4 * q);
        floatx4 c0 = acc[2 * hd], c1 = acc[2 * hd + 1];
        ps[hd] = c0[0] * as0.x + c0[1] * as0.y + c0[2] * as0.z + c0[3] * as0.w
               + c1[0] * as1.x + c1[1] * as1.y + c1[2] * as1.z + c1[3] * as1.w;
        pd[hd] = c0[0] * ad0.x + c0[1] * ad0.y + c0[2] * ad0.z + c0[3] * ad0.w
               + c1[0] * ad1.x + c1[1] * ad1.y + c1[2] * ad1.z + c1[3] * ad1.w;
    }
#pragma unroll
    for (int hd = 0; hd < 4; ++hd) {
        ps[hd] += __shfl_xor(ps[hd], 16);
        ps[hd] += __shfl_xor(ps[hd], 32);
        pd[hd] += __shfl_xor(pd[hd], 16);
        pd[hd] += __shfl_xor(pd[hd], 32);
    }
    const int node = rowBase + 16 * w + l15;
    if (node < N) {
        alpha_s[(size_t)node * 4 + q] = ps[q];
        alpha_d[(size_t)node * 4 + q] = pd[q];
    }
}

// ============================================================ prep + bucket count (fused)
__global__ __launch_bounds__(256) void prep_count_kernel(
    const float* __restrict__ W, const float* __restrict__ W1,
    const float* __restrict__ x, uint4* __restrict__ Wp,
    uint4* __restrict__ W1p, uint4* __restrict__ xb,
    const int* __restrict__ ei, int E, int NB,
    int* __restrict__ bucket_count, int L, int N, int nbPrep)
{
    __shared__ int cnt[256];
    if ((int)blockIdx.x >= nbPrep) {
        cnt[threadIdx.x] = 0;
        __syncthreads();
        const int base = (blockIdx.x - nbPrep) * 2048 + threadIdx.x;
#pragma unroll
        for (int j = 0; j < 8; ++j) {
            int idx = base + j * 256;
            if (idx < E) atomicAdd(&cnt[ei[E + idx] >> 8], 1);
        }
        __syncthreads();
        int c = cnt[threadIdx.x];
        if ((int)threadIdx.x < NB && c) atomicAdd(&bucket_count[threadIdx.x], c);
        return;
    }
    int id = blockIdx.x * 256 + threadIdx.x;
    const int nW = L * 2048;
    const int nX = N * 16;
    if (id < nW) {
        int l = id >> 11, s = id & 2047;
        int chunk = s >> 7, col = s & 127;
        const float* wp = W + (size_t)l * 16384 + (chunk * 8) * 128 + col;
        uint4 pk;
        pk.x = pack2(wp[0],   wp[128]);
        pk.y = pack2(wp[256], wp[384]);
        pk.z = pack2(wp[512], wp[640]);
        pk.w = pack2(wp[768], wp[896]);
        Wp[id] = pk;
    } else if (id < nW + 1024) {
        int s = id - nW;
        int chunk = s >> 5, col = s & 31;
        const float* wp = W1 + (chunk * 8) * 32 + col;
        uint4 pk;
        pk.x = pack2(wp[0],   wp[32]);
        pk.y = pack2(wp[64],  wp[96]);
        pk.z = pack2(wp[128], wp[160]);
        pk.w = pack2(wp[192], wp[224]);
        W1p[s] = pk;
    } else if (id < nW + 1024 + nX) {
        int xid = id - nW - 1024;
        int row = xid >> 4, c8 = xid & 15;
        const float4* xp = (const float4*)(x + (size_t)row * 128 + c8 * 8);
        float4 v0 = xp[0], v1 = xp[1];
        uint4 pk;
        pk.x = pack2(v0.x, v0.y); pk.y = pack2(v0.z, v0.w);
        pk.z = pack2(v1.x, v1.y); pk.w = pack2(v1.z, v1.w);
        xb[xid] = pk;
    }
}

// ============================================================ distribute (standalone)
__global__ __launch_bounds__(256) void dist_kernel(
    const int* __restrict__ ei, int E, int NB,
    const int* __restrict__ bucket_count, int* __restrict__ bucket_cursor,
    uint* __restrict__ bdata)
{
    __shared__ int cnt[256];
    __shared__ int sc[256];
    __shared__ int bb[256];
    const int t = threadIdx.x;
    cnt[t] = 0;
    __syncthreads();
    const int base = blockIdx.x * 2048 + t;
    int srcs[8], dsts[8], rank[8];
#pragma unroll
    for (int j = 0; j < 8; ++j) {
        int idx = base + j * 256;
        if (idx < E) {
            srcs[j] = ei[idx];
            dsts[j] = ei[E + idx];
            rank[j] = atomicAdd(&cnt[dsts[j] >> 8], 1);
        } else dsts[j] = -1;
    }
    __syncthreads();
    int bc = (t < NB) ? bucket_count[t] : 0;
    sc[t] = bc;
    __syncthreads();
    for (int off = 1; off < 256; off <<= 1) {
        int x = sc[t];
        int a = (t >= off) ? sc[t - off] : 0;
        __syncthreads();
        sc[t] = x + a;
        __syncthreads();
    }
    int gbase = sc[t] - bc;
    int c = cnt[t];
    bb[t] = (t < NB && c) ? (gbase + atomicAdd(&bucket_cursor[t], c)) : 0;
    __syncthreads();
    // plain stores: scattered 4B pattern NEEDS L2 write-combining (r14: NT
    // here caused 78 MB of partial-line writebacks, +50 µs)
#pragma unroll
    for (int j = 0; j < 8; ++j) {
        if (dsts[j] >= 0) {
            int b = dsts[j] >> 8;
            bdata[bb[b] + rank[j]] = (uint)srcs[j] | ((uint)(dsts[j] & 255) << 16);
        }
    }
}

// ============================================================ bucket->CSR + gemm l0 (grid-fused)
#define BCAP 12800
__global__ __launch_bounds__(256) void csr_gemm_kernel(
    const uint* __restrict__ bdata, const int* __restrict__ bucket_count,
    int NB, int E, int* __restrict__ row_start, ushort* __restrict__ csr_src,
    const uint4* __restrict__ xb, const uint4* __restrict__ Wp,
    const float* __restrict__ att_s, const float* __restrict__ att_d,
    uint* __restrict__ h2, float* __restrict__ alpha_s,
    float* __restrict__ alpha_d, int N)
{
    __shared__ __align__(16) char smraw[GA_LDS_BYTES];   // 49408 B, overlaid
    const int t = threadIdx.x;
    if ((int)blockIdx.x >= NB) {
        gemm_body(smraw, xb, Wp, att_s, att_d, h2, alpha_s, alpha_d, N,
                  (blockIdx.x - NB) * 64);
        return;
    }
    int* hist = (int*)smraw;                 // 2048
    int* cur  = hist + 2048;                 // 2048
    int* scn  = cur + 2048;                  // 256
    int* sb   = scn + 256;                   // 256
    ushort* buf = (ushort*)(sb + 256);       // BCAP (25600 B) -> total 44032
    const int b = blockIdx.x;

    int bc = (t < NB) ? bucket_count[t] : 0;
    sb[t] = bc;
    __syncthreads();
    for (int off = 1; off < 256; off <<= 1) {
        int x = sb[t];
        int a = (t >= off) ? sb[t - off] : 0;
        __syncthreads();
        sb[t] = x + a;
        __syncthreads();
    }
    const int beg = (b > 0) ? sb[b - 1] : 0;
    const int sz = sb[b] - beg;
    if (b == 0 && t == 0) row_start[N] = E;

#pragma unroll
    for (int j = 0; j < 8; ++j) hist[t * 8 + j] = 0;
    __syncthreads();
    for (int i = t; i < sz; i += 256) {
        uint d = bdata[beg + i];
        int key = (int)((d >> 16) << 3) | (int)((d & 0xFFFFu) >> SEG_SHIFT);
        atomicAdd(&hist[key], 1);
    }
    __syncthreads();
    int local[8]; int s = 0;
#pragma unroll
    for (int j = 0; j < 8; ++j) { local[j] = hist[t * 8 + j]; s += local[j]; }
    scn[t] = s;
    __syncthreads();
    for (int off = 1; off < 256; off <<= 1) {
        int x = scn[t];
        int a = (t >= off) ? scn[t - off] : 0;
        __syncthreads();
        scn[t] = x + a;
        __syncthreads();
    }
    int run = scn[t] - s;
#pragma unroll
    for (int j = 0; j < 8; ++j) { cur[t * 8 + j] = run; run += local[j]; }
    __syncthreads();
    int node = b * 256 + t;
    if (node < N) row_start[node] = beg + cur[t << 3];
    __syncthreads();
    if (sz <= BCAP) {
        for (int i = t; i < sz; i += 256) {
            uint d = bdata[beg + i];
            int key = (int)((d >> 16) << 3) | (int)((d & 0xFFFFu) >> SEG_SHIFT);
            int pos = atomicAdd(&cur[key], 1);
            buf[pos] = (ushort)(d & 0xFFFFu);
        }
        __syncthreads();
        for (int i = t; i < sz; i += 256)
            __builtin_nontemporal_store(buf[i], &csr_src[beg + i]);
    } else {
        for (int i = t; i < sz; i += 256) {
            uint d = bdata[beg + i];
            int key = (int)((d >> 16) << 3) | (int)((d & 0xFFFFu) >> SEG_SHIFT);
            int pos = atomicAdd(&cur[key], 1);
            csr_src[beg + pos] = (ushort)(d & 0xFFFFu);
        }
    }
}

// ============================================================ agg core (computes a0..a7, sx)
static __device__ __forceinline__ void agg_core(
    const ushort* __restrict__ csr_src, const int* __restrict__ row_start,
    const float* __restrict__ alpha_s, const float* __restrict__ alpha_d,
    const uint* __restrict__ h2, int g, int l, int head,
    float& a0, float& a1, float& a2, float& a3,
    float& a4, float& a5, float& a6, float& a7, float& sx)
{
    const char* hbase = (const char*)h2 + (size_t)l * 16;
    const float ad = alpha_d[g * 4 + head];

    float e = alpha_s[g * 4 + head] + ad;
    e = e > 0.f ? e : NEG_SLOPE * e;
    float ex = __expf(e);
    uint4 q = *(const uint4*)(hbase + (uint)g * 256u);
    a0 = ex * bf_lo(q.x); a1 = ex * bf_hi(q.x);
    a2 = ex * bf_lo(q.y); a3 = ex * bf_hi(q.y);
    a4 = ex * bf_lo(q.z); a5 = ex * bf_hi(q.z);
    a6 = ex * bf_lo(q.w); a7 = ex * bf_hi(q.w);
    sx = ex;

    const int beg = row_start[g];
    const int end = row_start[g + 1];
    int k = beg;
    for (; k + 4 <= end; k += 4) {
        uint s0 = csr_src[k], s1 = csr_src[k + 1];
        uint s2 = csr_src[k + 2], s3 = csr_src[k + 3];
        uint4 q0 = *(const uint4*)(hbase + s0 * 256u);
        uint4 q1 = *(const uint4*)(hbase + s1 * 256u);
        uint4 q2 = *(const uint4*)(hbase + s2 * 256u);
        uint4 q3 = *(const uint4*)(hbase + s3 * 256u);
        float e0 = alpha_s[s0 * 4 + head] + ad;
        float e1 = alpha_s[s1 * 4 + head] + ad;
        float e2 = alpha_s[s2 * 4 + head] + ad;
        float e3 = alpha_s[s3 * 4 + head] + ad;
        e0 = e0 > 0.f ? e0 : NEG_SLOPE * e0;
        e1 = e1 > 0.f ? e1 : NEG_SLOPE * e1;
        e2 = e2 > 0.f ? e2 : NEG_SLOPE * e2;
        e3 = e3 > 0.f ? e3 : NEG_SLOPE * e3;
        float x0 = __expf(e0), x1 = __expf(e1);
        float x2 = __expf(e2), x3 = __expf(e3);
        a0 += x0 * bf_lo(q0.x) + x1 * bf_lo(q1.x) + x2 * bf_lo(q2.x) + x3 * bf_lo(q3.x);
        a1 += x0 * bf_hi(q0.x) + x1 * bf_hi(q1.x) + x2 * bf_hi(q2.x) + x3 * bf_hi(q3.x);
        a2 += x0 * bf_lo(q0.y) + x1 * bf_lo(q1.y) + x2 * bf_lo(q2.y) + x3 * bf_lo(q3.y);
        a3 += x0 * bf_hi(q0.y) + x1 * bf_hi(q1.y) + x2 * bf_hi(q2.y) + x3 * bf_hi(q3.y);
        a4 += x0 * bf_lo(q0.z) + x1 * bf_lo(q1.z) + x2 * bf_lo(q2.z) + x3 * bf_lo(q3.z);
        a5 += x0 * bf_hi(q0.z) + x1 * bf_hi(q1.z) + x2 * bf_hi(q2.z) + x3 * bf_hi(q3.z);
        a6 += x0 * bf_lo(q0.w) + x1 * bf_lo(q1.w) + x2 * bf_lo(q2.w) + x3 * bf_lo(q3.w);
        a7 += x0 * bf_hi(q0.w) + x1 * bf_hi(q1.w) + x2 * bf_hi(q2.w) + x3 * bf_hi(q3.w);
        sx += x0 + x1 + x2 + x3;
    }
    for (; k < end; ++k) {
        uint s0 = csr_src[k];
        float e0 = alpha_s[s0 * 4 + head] + ad;
        uint4 q0 = *(const uint4*)(hbase + s0 * 256u);
        e0 = e0 > 0.f ? e0 : NEG_SLOPE * e0;
        float x0 = __expf(e0);
        a0 += x0 * bf_lo(q0.x); a1 += x0 * bf_hi(q0.x);
        a2 += x0 * bf_lo(q0.y); a3 += x0 * bf_hi(q0.y);
        a4 += x0 * bf_lo(q0.z); a5 += x0 * bf_hi(q0.z);
        a6 += x0 * bf_lo(q0.w); a7 += x0 * bf_hi(q0.w);
        sx += x0;
    }
}

// ============================================================ agg + fused next-layer GEMM
// Alpha ping-pong (separate buffers — cross-block race otherwise). h2out
// staged via LDS -> coalesced uint4 full-line stores (no write-allocate).
__global__ __launch_bounds__(256) void aggemm_kernel(
    const ushort* __restrict__ csr_src, const int* __restrict__ row_start,
    const float* __restrict__ alpha_s, const float* __restrict__ alpha_d,
    const uint* __restrict__ h2in, const float* __restrict__ b,
    const uint4* __restrict__ Wnext,
    const float* __restrict__ att_s, const float* __restrict__ att_d,
    uint* __restrict__ h2out, float* __restrict__ alpha_s_out,
    float* __restrict__ alpha_d_out, int N)
{
    __shared__ __align__(16) uint4 tile[16 * 17];   // frag tile; reused as stage
    const int t = threadIdx.x;
    const int nodeBase = blockIdx.x * 16;
    const int gl = t >> 4;
    const int g = nodeBase + gl;
    const int l = t & 15;
    const bool active = g < N;

    uint4 o = make_uint4(0u, 0u, 0u, 0u);
    if (active) {
        float a0, a1, a2, a3, a4, a5, a6, a7, sx;
        agg_core(csr_src, row_start, alpha_s, alpha_d, h2in, g, l, l >> 2,
                 a0, a1, a2, a3, a4, a5, a6, a7, sx);
        const float inv = 1.f / (sx + EPSF);
        const float4 b0 = ((const float4*)b)[l * 2];
        const float4 b1 = ((const float4*)b)[l * 2 + 1];
        o.x = pack2(b0.x + a0 * inv, b0.y + a1 * inv);
        o.y = pack2(b0.z + a2 * inv, b0.w + a3 * inv);
        o.z = pack2(b1.x + a4 * inv, b1.y + a5 * inv);
        o.w = pack2(b1.z + a6 * inv, b1.w + a7 * inv);
    }
    tile[gl * 17 + l] = o;
    __syncthreads();

    const int w = t >> 6, lane = t & 63, q = lane >> 4, l15 = lane & 15;
    floatx4 acc0 = (floatx4){0.f, 0.f, 0.f, 0.f};
    floatx4 acc1 = (floatx4){0.f, 0.f, 0.f, 0.f};
#pragma unroll
    for (int s = 0; s < 4; ++s) {
        short8 xfr = u2s8(tile[l15 * 17 + 4 * s + q]);
        short8 wf0 = u2s8(Wnext[(4 * s + q) * 128 + 16 * (2 * w) + l15]);
        short8 wf1 = u2s8(Wnext[(4 * s + q) * 128 + 16 * (2 * w + 1) + l15]);
        acc0 = __builtin_amdgcn_mfma_f32_16x16x32_bf16(wf0, xfr, acc0, 0, 0, 0);
        acc1 = __builtin_amdgcn_mfma_f32_16x16x32_bf16(wf1, xfr, acc1, 0, 0, 0);
    }
    __syncthreads();   // tile reads done; reuse as output stage (16 x 65 uints)

    uint* stg = (uint*)tile;
    {
        uint2 o0, o1;
        o0.x = pack2(acc0[0], acc0[1]); o0.y = pack2(acc0[2], acc0[3]);
        o1.x = pack2(acc1[0], acc1[1]); o1.y = pack2(acc1[2], acc1[3]);
        *(uint2*)(stg + l15 * 65 + 16 * w + 2 * q) = o0;
        *(uint2*)(stg + l15 * 65 + 16 * w + 8 + 2 * q) = o1;
    }
    __syncthreads();
    // coalesced copy-out: thread t -> node t>>4, chunk t&15 (full 64B lines)
    {
        int nl = t >> 4, c8 = t & 15;
        if (nodeBase + nl < N)
            ((uint4*)(h2out + (size_t)(nodeBase + nl) * 64))[c8] =
                *(const uint4*)(stg + nl * 65 + 4 * c8);
    }

    const float4 as0 = *(const float4*)(att_s + 32 * w + 4 * q);
    const float4 as1 = *(const float4*)(att_s + 32 * w + 16 + 4 * q);
    const float4 ad0 = *(const float4*)(att_d + 32 * w + 4 * q);
    const float4 ad1 = *(const float4*)(att_d + 32 * w + 16 + 4 * q);
    float ps = acc0[0] * as0.x + acc0[1] * as0.y + acc0[2] * as0.z + acc0[3] * as0.w
             + acc1[0] * as1.x + acc1[1] * as1.y + acc1[2] * as1.z + acc1[3] * as1.w;
    float pd = acc0[0] * ad0.x + acc0[1] * ad0.y + acc0[2] * ad0.z + acc0[3] * ad0.w
             + acc1[0] * ad1.x + acc1[1] * ad1.y + acc1[2] * ad1.z + acc1[3] * ad1.w;
    ps += __shfl_xor(ps, 16); ps += __shfl_xor(ps, 32);
    pd += __shfl_xor(pd, 16); pd += __shfl_xor(pd, 32);
    const int node = nodeBase + l15;
    if (node < N && q == 0) {
        alpha_s_out[(size_t)node * 4 + w] = ps;
        alpha_d_out[(size_t)node * 4 + w] = pd;
    }
}

// ============================================================ final agg + MLP (fused)
__global__ __launch_bounds__(256) void aggmlp_kernel(
    const ushort* __restrict__ csr_src, const int* __restrict__ row_start,
    const float* __restrict__ alpha_s, const float* __restrict__ alpha_d,
    const uint* __restrict__ h2in, const float* __restrict__ b,
    const uint4* __restrict__ xb0, const uint4* __restrict__ W1p,
    const float* __restrict__ b1, const float* __restrict__ W2,
    const float* __restrict__ b2, float* __restrict__ out, int N)
{
    __shared__ __align__(16) uint4 tile[16 * 33];   // [node][32 chunks, pad 33]
    __shared__ float pr[32];
    const int t = threadIdx.x;
    const int nodeBase = blockIdx.x * 16;
    const int gl = t >> 4;
    const int g = nodeBase + gl;
    const int l = t & 15;

    // x0 rows -> chunks 16..31 (nontemporal read: read-once, keep L2 for h2in)
    {
        uintx4 v = (uintx4){0u, 0u, 0u, 0u};
        if (g < N)
            v = __builtin_nontemporal_load(
                (const uintx4*)(xb0 + (size_t)g * 16 + l));
        union { uintx4 x; uint4 u; } cc; cc.x = v;
        tile[gl * 33 + 16 + l] = cc.u;
    }

    uint4 o = make_uint4(0u, 0u, 0u, 0u);
    if (g < N) {
        float a0, a1, a2, a3, a4, a5, a6, a7, sx;
        agg_core(csr_src, row_start, alpha_s, alpha_d, h2in, g, l, l >> 2,
                 a0, a1, a2, a3, a4, a5, a6, a7, sx);
        const float inv = 1.f / (sx + EPSF);
        const float4 b0 = ((const float4*)b)[l * 2];
        const float4 b1v = ((const float4*)b)[l * 2 + 1];
        o.x = pack2(b0.x + a0 * inv, b0.y + a1 * inv);
        o.y = pack2(b0.z + a2 * inv, b0.w + a3 * inv);
        o.z = pack2(b1v.x + a4 * inv, b1v.y + a5 * inv);
        o.w = pack2(b1v.z + a6 * inv, b1v.w + a7 * inv);
    }
    tile[gl * 33 + l] = o;
    __syncthreads();

    const int w = t >> 6, lane = t & 63, q = lane >> 4, l15 = lane & 15;
    if (w < 2) {
        floatx4 acc = (floatx4){0.f, 0.f, 0.f, 0.f};
#pragma unroll
        for (int s = 0; s < 8; ++s) {
            short8 a = u2s8(tile[l15 * 33 + 4 * s + q]);
            short8 bb = u2s8(W1p[(4 * s + q) * 32 + 16 * w + l15]);
            acc = __builtin_amdgcn_mfma_f32_16x16x32_bf16(a, bb, acc, 0, 0, 0);
        }
        const int col = 16 * w + l15;
        const float b1c = b1[col], w2c = W2[col];
#pragma unroll
        for (int r = 0; r < 4; ++r) {
            float v = acc[r] + b1c;
            v = v > 0.f ? v : 0.f;
            float p = v * w2c;
            p += __shfl_xor(p, 1);
            p += __shfl_xor(p, 2);
            p += __shfl_xor(p, 4);
            p += __shfl_xor(p, 8);
            if (l15 == 0) pr[w * 16 + 4 * q + r] = p;
        }
    }
    __syncthreads();
    if (t < 16) {
        int node = nodeBase + t;
        if (node < N) {
            float z = pr[t] + pr[16 + t] + b2[0];
            out[node] = 1.f / (1.f + __expf(-z));
        }
    }
}

// ============================================================ launch
extern "C" void kernel_launch(void* const* d_in, const int* in_sizes, int n_in,
                              void* d_out, int out_size, void* d_ws, size_t ws_size,
                              hipStream_t stream)
{
    const float* x       = (const float*)d_in[0];
    const int*   ei      = (const int*)d_in[1];
    const float* W       = (const float*)d_in[2];
    const float* att_src = (const float*)d_in[3];
    const float* att_dst = (const float*)d_in[4];
    const float* b_conv  = (const float*)d_in[5];
    const float* W1      = (const float*)d_in[6];
    const float* b1      = (const float*)d_in[7];
    const float* W2      = (const float*)d_in[8];
    const float* b2      = (const float*)d_in[9];
    float* outp = (float*)d_out;

    const int N = in_sizes[0] / 128;
    const int E = in_sizes[1] / 2;
    const int L = in_sizes[2] / (128 * 128);
    const int NB = (N + 255) >> 8;

    char* ws = (char*)d_ws;
    uint*  h2a      = (uint*)ws;                          // N*64 uints
    uint*  h2b      = h2a + (size_t)N * 64;               // N*64 uints (ping-pong)
    uint4* xb0      = (uint4*)(h2b + (size_t)N * 64);     // N*16 uint4 (bf16 x)
    float* alphaA_s = (float*)(xb0 + (size_t)N * 16);     // N*4
    float* alphaA_d = alphaA_s + (size_t)N * 4;           // N*4
    float* alphaB_s = alphaA_d + (size_t)N * 4;           // N*4
    float* alphaB_d = alphaB_s + (size_t)N * 4;           // N*4
    uint4* Wp       = (uint4*)(alphaB_d + (size_t)N * 4); // L*2048
    uint4* W1p      = Wp + (size_t)L * 2048;              // 1024
    int* bucket_count  = (int*)(W1p + 1024);              // 256
    int* bucket_cursor = bucket_count + 256;              // 256
    int* row_start     = bucket_cursor + 256;             // N+1
    uint* bdata        = (uint*)(row_start + N + 1);      // E
    ushort* csr_src    = (ushort*)(bdata + E);            // E

    const int nbE = (E + 2047) / 2048;
    const int gBlocks = (N + 63) / 64;
    const int aggBlocks = (N + 15) / 16;
    const int prepItems = L * 2048 + 1024 + N * 16;
    const int nbPrep = (prepItems + 255) / 256;

    (void)hipMemsetAsync(bucket_count, 0, 512 * sizeof(int), stream);

    prep_count_kernel<<<nbPrep + nbE, 256, 0, stream>>>(
        W, W1, x, Wp, W1p, xb0, ei, E, NB, bucket_count, L, N, nbPrep);

    dist_kernel<<<nbE, 256, 0, stream>>>(ei, E, NB, bucket_count,
                                         bucket_cursor, bdata);

    // bucket->CSR overlapped with gemm layer 0
    csr_gemm_kernel<<<NB + gBlocks, 256, 0, stream>>>(
        bdata, bucket_count, NB, E, row_start, csr_src,
        xb0, Wp, att_src, att_dst, h2a, alphaA_s, alphaA_d, N);

    // layer 0: read h2a/alphaA -> write h2b/alphaB
    aggemm_kernel<<<aggBlocks, 256, 0, stream>>>(
        csr_src, row_start, alphaA_s, alphaA_d, h2a,
        b_conv + 0 * 128, Wp + (size_t)1 * 2048,
        att_src + (size_t)1 * 128, att_dst + (size_t)1 * 128,
        h2b, alphaB_s, alphaB_d, N);

    // layer 1: read h2b/alphaB -> write h2a/alphaA
    aggemm_kernel<<<aggBlocks, 256, 0, stream>>>(
        csr_src, row_start, alphaB_s, alphaB_d, h2b,
        b_conv + (size_t)1 * 128, Wp + (size_t)2 * 2048,
        att_src + (size_t)2 * 128, att_dst + (size_t)2 * 128,
        h2a, alphaA_s, alphaA_d, N);

    // layer 2 + MLP fused
    aggmlp_kernel<<<aggBlocks, 256, 0, stream>>>(
        csr_src, row_start, alphaA_s, alphaA_d, h2a,
        b_conv + (size_t)2 * 128, xb0, W1p, b1, W2, b2, outp, N);
}